// Round 1
// baseline (1496.348 us; speedup 1.0000x reference)
//
#include <hip/hip_runtime.h>
#include <hip/hip_bf16.h>
#include <stdint.h>

#define HH 80
#define WW 80
#define LL 6400
#define CC 32
#define K9 288          // CC*9
#define BB 2
#define TM 64
#define TL 64
#define NSPLIT 5
#define LSPLIT (LL / NSPLIT)   // 1280
#define NTILES (LSPLIT / TL)   // 20
#define COG 8

__device__ __forceinline__ int div80(int v) {
    return (int)(((unsigned)v * 52429u) >> 22);   // exact for 0 <= v < 52428
}

// ---------------- prep: inverse column norms of unfold(HSI), unfold(PAN) ----------------
__global__ void prep_kernel(const float* __restrict__ HSI, const float* __restrict__ PAN,
                            float* __restrict__ invH, float* __restrict__ invP) {
    int g = blockIdx.x * blockDim.x + threadIdx.x;
    if (g >= BB * LL) return;
    int b = g / LL, l = g - b * LL;
    int y = div80(l), x = l - y * 80;
    const float* Hb = HSI + (size_t)b * CC * LL;
    const float* Pb = PAN + (size_t)b * CC * LL;
    float sh = 0.f, sp = 0.f;
    for (int c = 0; c < CC; ++c) {
        const float* hc = Hb + c * LL;
        const float* pc = Pb + c * LL;
        #pragma unroll
        for (int i = 0; i < 3; ++i) {
            int yy = y + i - 1;
            if ((unsigned)yy >= 80u) continue;
            #pragma unroll
            for (int j = 0; j < 3; ++j) {
                int xx = x + j - 1;
                if ((unsigned)xx >= 80u) continue;
                float hv = hc[yy * 80 + xx]; sh = fmaf(hv, hv, sh);
                float pv = pc[yy * 80 + xx]; sp = fmaf(pv, pv, sp);
            }
        }
    }
    invH[g] = 1.f / fmaxf(sqrtf(sh), 1e-12f);
    invP[g] = 1.f / fmaxf(sqrtf(sp), 1e-12f);
}

// ---------------- sim: fused similarity GEMM + column max/argmax ----------------
// R[l,m] = (PAN_col(l)*invP[l]) . HSI_col(m); per (b,m): max over l-range, first-argmax.
__global__ __launch_bounds__(256) void sim_kernel(const float* __restrict__ HSI,
                                                  const float* __restrict__ PAN,
                                                  const float* __restrict__ invP,
                                                  float* __restrict__ pVal,
                                                  int* __restrict__ pArg) {
    __shared__ __align__(16) float Bm[K9][TM];   // HSI tile (raw)
    __shared__ __align__(16) float Al[K9][TL];   // PAN tile (scaled by invP)
    const int mt  = blockIdx.x;   // 0..99
    const int sp  = blockIdx.y;   // 0..NSPLIT-1
    const int b   = blockIdx.z;   // 0..1
    const int tid = threadIdx.x;
    const float* Hb = HSI + (size_t)b * CC * LL;
    const float* Pb = PAN + (size_t)b * CC * LL;

    // stage HSI m-tile once: thread (li = tid&63) covers 8 channels x 9 taps
    {
        const int li = tid & 63;
        const int m  = mt * TM + li;
        const int y  = div80(m), x = m - y * 80;
        const int cbase = (tid >> 6) * 8;
        for (int c = cbase; c < cbase + 8; ++c) {
            const float* img = Hb + c * LL;
            int k = c * 9;
            #pragma unroll
            for (int i = 0; i < 3; ++i)
                #pragma unroll
                for (int j = 0; j < 3; ++j) {
                    int yy = y + i - 1, xx = x + j - 1;
                    float v = 0.f;
                    if ((unsigned)yy < 80u && (unsigned)xx < 80u) v = img[yy * 80 + xx];
                    Bm[k][li] = v; ++k;
                }
        }
    }

    const int tm = tid & 15, tl = tid >> 4;
    float best[4]; int bestl[4];
    #pragma unroll
    for (int i = 0; i < 4; ++i) { best[i] = -3.0e38f; bestl[i] = 0; }

    for (int t = 0; t < NTILES; ++t) {
        const int l0 = sp * LSPLIT + t * TL;
        // stage PAN l-tile, scaled by invP[l]
        {
            const int li = tid & 63;
            const int l  = l0 + li;
            const float s = invP[b * LL + l];
            const int y  = div80(l), x = l - y * 80;
            const int cbase = (tid >> 6) * 8;
            for (int c = cbase; c < cbase + 8; ++c) {
                const float* img = Pb + c * LL;
                int k = c * 9;
                #pragma unroll
                for (int i = 0; i < 3; ++i)
                    #pragma unroll
                    for (int j = 0; j < 3; ++j) {
                        int yy = y + i - 1, xx = x + j - 1;
                        float v = 0.f;
                        if ((unsigned)yy < 80u && (unsigned)xx < 80u) v = img[yy * 80 + xx];
                        Al[k][li] = v * s; ++k;
                    }
            }
        }
        __syncthreads();

        float acc[4][4];
        #pragma unroll
        for (int i = 0; i < 4; ++i)
            #pragma unroll
            for (int j = 0; j < 4; ++j) acc[i][j] = 0.f;

        #pragma unroll 4
        for (int k = 0; k < K9; ++k) {
            const float4 a4 = *reinterpret_cast<const float4*>(&Al[k][tl * 4]);
            const float4 b4 = *reinterpret_cast<const float4*>(&Bm[k][tm * 4]);
            float av[4] = {a4.x, a4.y, a4.z, a4.w};
            float bv[4] = {b4.x, b4.y, b4.z, b4.w};
            #pragma unroll
            for (int mi = 0; mi < 4; ++mi)
                #pragma unroll
                for (int li2 = 0; li2 < 4; ++li2)
                    acc[mi][li2] = fmaf(bv[mi], av[li2], acc[mi][li2]);
        }

        // running max over this tile's l values (ascending l + strict > == first-max)
        #pragma unroll
        for (int li2 = 0; li2 < 4; ++li2) {
            const int labs = l0 + tl * 4 + li2;
            #pragma unroll
            for (int mi = 0; mi < 4; ++mi) {
                const float v = acc[mi][li2];
                if (v > best[mi]) { best[mi] = v; bestl[mi] = labs; }
            }
        }
        __syncthreads();   // protect Al before next stage / final scratch reuse
    }

    // block-level reduction across tl (16 per m), ascending l with tie -> smaller l
    float* sval = &Al[0][0];                           // 64*16 floats
    int*   sarg = reinterpret_cast<int*>(&Al[16][0]);  // next 1024 slots
    #pragma unroll
    for (int mi = 0; mi < 4; ++mi) {
        sval[(tm * 4 + mi) * 16 + tl] = best[mi];
        sarg[(tm * 4 + mi) * 16 + tl] = bestl[mi];
    }
    __syncthreads();
    if (tid < TM) {
        float bv = -3.0e38f; int ba = 0x7fffffff;
        #pragma unroll
        for (int q = 0; q < 16; ++q) {
            float v = sval[tid * 16 + q]; int a = sarg[tid * 16 + q];
            if (v > bv || (v == bv && a < ba)) { bv = v; ba = a; }
        }
        const int m = mt * TM + tid;
        pVal[(b * LL + m) * NSPLIT + sp] = bv;
        pArg[(b * LL + m) * NSPLIT + sp] = ba;
    }
}

// ---------------- merge splits -> S (scaled by invH) and argmax ----------------
__global__ void merge_kernel(const float* __restrict__ pVal, const int* __restrict__ pArg,
                             const float* __restrict__ invH,
                             float* __restrict__ Sv, int* __restrict__ Sa) {
    int g = blockIdx.x * blockDim.x + threadIdx.x;
    if (g >= BB * LL) return;
    float bv = -3.0e38f; int ba = 0x7fffffff;
    #pragma unroll
    for (int s = 0; s < NSPLIT; ++s) {
        float v = pVal[g * NSPLIT + s]; int a = pArg[g * NSPLIT + s];
        if (v > bv || (v == bv && a < ba)) { bv = v; ba = a; }
    }
    Sv[g] = bv * invH[g];
    Sa[g] = ba;
}

// ---------------- T_lv3 = fold3x3(gathered PAN patches) / 9 ----------------
__global__ void tfold_kernel(const float* __restrict__ PAN, const int* __restrict__ Sa,
                             float* __restrict__ T) {
    int g = blockIdx.x * blockDim.x + threadIdx.x;
    if (g >= BB * CC * LL) return;
    int bc = g / LL, l = g - bc * LL;
    int b = bc >> 5;              // / CC
    int y = div80(l), x = l - y * 80;
    const float* img = PAN + (size_t)bc * LL;
    const int* Sab = Sa + b * LL;
    float acc = 0.f;
    #pragma unroll
    for (int i = 0; i < 3; ++i) {
        int yp = y + 1 - i;
        if ((unsigned)yp >= 80u) continue;
        #pragma unroll
        for (int j = 0; j < 3; ++j) {
            int xp = x + 1 - j;
            if ((unsigned)xp >= 80u) continue;
            int a = Sab[yp * 80 + xp];
            int ya = div80(a), xa = a - ya * 80;
            int py = ya + i - 1, px = xa + j - 1;
            if ((unsigned)py < 80u && (unsigned)px < 80u) acc += img[py * 80 + px];
        }
    }
    T[g] = acc * (1.f / 9.f);
}

// ---------------- conv1: h = relu(conv3x3(concat(T,HSI), w1) + b1) ----------------
__global__ __launch_bounds__(256) void conv1_kernel(const float* __restrict__ T,
                                                    const float* __restrict__ HSI,
                                                    const float* __restrict__ w1,
                                                    const float* __restrict__ b1,
                                                    float* __restrict__ h) {
    __shared__ __align__(16) float wl[64][9][COG];   // 18.4 KB
    const int tid = threadIdx.x;
    const int co0 = blockIdx.y * COG;
    for (int idx = tid; idx < 64 * 9 * COG; idx += 256) {
        int cog = idx & (COG - 1);
        int rest = idx >> 3;
        int cin = rest / 9, tap = rest - cin * 9;
        wl[cin][tap][cog] = w1[(co0 + cog) * (64 * 9) + cin * 9 + tap];
    }
    __syncthreads();
    const int g = blockIdx.x * 256 + tid;      // 0..12799
    const int b = g / LL, l = g - b * LL;
    const int y = div80(l), x = l - y * 80;
    float acc[COG];
    #pragma unroll
    for (int i = 0; i < COG; ++i) acc[i] = 0.f;
    for (int cin = 0; cin < 64; ++cin) {
        const float* img = (cin < CC) ? (T + (size_t)(b * CC + cin) * LL)
                                      : (HSI + (size_t)(b * CC + (cin - CC)) * LL);
        float tap[9];
        #pragma unroll
        for (int i = 0; i < 3; ++i)
            #pragma unroll
            for (int j = 0; j < 3; ++j) {
                int yy = y + i - 1, xx = x + j - 1;
                tap[i * 3 + j] = ((unsigned)yy < 80u && (unsigned)xx < 80u) ? img[yy * 80 + xx] : 0.f;
            }
        #pragma unroll
        for (int t9 = 0; t9 < 9; ++t9) {
            const float4 wa = *reinterpret_cast<const float4*>(&wl[cin][t9][0]);
            const float4 wb = *reinterpret_cast<const float4*>(&wl[cin][t9][4]);
            acc[0] = fmaf(tap[t9], wa.x, acc[0]);
            acc[1] = fmaf(tap[t9], wa.y, acc[1]);
            acc[2] = fmaf(tap[t9], wa.z, acc[2]);
            acc[3] = fmaf(tap[t9], wa.w, acc[3]);
            acc[4] = fmaf(tap[t9], wb.x, acc[4]);
            acc[5] = fmaf(tap[t9], wb.y, acc[5]);
            acc[6] = fmaf(tap[t9], wb.z, acc[6]);
            acc[7] = fmaf(tap[t9], wb.w, acc[7]);
        }
    }
    #pragma unroll
    for (int cog = 0; cog < COG; ++cog) {
        float v = acc[cog] + b1[co0 + cog];
        h[(size_t)(b * CC + co0 + cog) * LL + l] = fmaxf(v, 0.f);
    }
}

// ---------------- conv2: out = (conv3x3(h, w2) + b2) * S + HSI ----------------
__global__ __launch_bounds__(256) void conv2_kernel(const float* __restrict__ hbuf,
                                                    const float* __restrict__ HSI,
                                                    const float* __restrict__ Sv,
                                                    const float* __restrict__ w2,
                                                    const float* __restrict__ b2,
                                                    float* __restrict__ out) {
    __shared__ __align__(16) float wl[CC][9][COG];   // 9.2 KB
    const int tid = threadIdx.x;
    const int co0 = blockIdx.y * COG;
    for (int idx = tid; idx < CC * 9 * COG; idx += 256) {
        int cog = idx & (COG - 1);
        int rest = idx >> 3;
        int cin = rest / 9, tap = rest - cin * 9;
        wl[cin][tap][cog] = w2[(co0 + cog) * (CC * 9) + cin * 9 + tap];
    }
    __syncthreads();
    const int g = blockIdx.x * 256 + tid;
    const int b = g / LL, l = g - b * LL;
    const int y = div80(l), x = l - y * 80;
    float acc[COG];
    #pragma unroll
    for (int i = 0; i < COG; ++i) acc[i] = 0.f;
    for (int cin = 0; cin < CC; ++cin) {
        const float* img = hbuf + (size_t)(b * CC + cin) * LL;
        float tap[9];
        #pragma unroll
        for (int i = 0; i < 3; ++i)
            #pragma unroll
            for (int j = 0; j < 3; ++j) {
                int yy = y + i - 1, xx = x + j - 1;
                tap[i * 3 + j] = ((unsigned)yy < 80u && (unsigned)xx < 80u) ? img[yy * 80 + xx] : 0.f;
            }
        #pragma unroll
        for (int t9 = 0; t9 < 9; ++t9) {
            const float4 wa = *reinterpret_cast<const float4*>(&wl[cin][t9][0]);
            const float4 wb = *reinterpret_cast<const float4*>(&wl[cin][t9][4]);
            acc[0] = fmaf(tap[t9], wa.x, acc[0]);
            acc[1] = fmaf(tap[t9], wa.y, acc[1]);
            acc[2] = fmaf(tap[t9], wa.z, acc[2]);
            acc[3] = fmaf(tap[t9], wa.w, acc[3]);
            acc[4] = fmaf(tap[t9], wb.x, acc[4]);
            acc[5] = fmaf(tap[t9], wb.y, acc[5]);
            acc[6] = fmaf(tap[t9], wb.z, acc[6]);
            acc[7] = fmaf(tap[t9], wb.w, acc[7]);
        }
    }
    const float s = Sv[b * LL + l];
    #pragma unroll
    for (int cog = 0; cog < COG; ++cog) {
        int c = co0 + cog;
        out[(size_t)(b * CC + c) * LL + l] = fmaf(acc[cog] + b2[c], s, HSI[(size_t)(b * CC + c) * LL + l]);
    }
}

extern "C" void kernel_launch(void* const* d_in, const int* in_sizes, int n_in,
                              void* d_out, int out_size, void* d_ws, size_t ws_size,
                              hipStream_t stream) {
    const float* HSI = (const float*)d_in[0];
    const float* PAN = (const float*)d_in[1];
    const float* w1  = (const float*)d_in[2];
    const float* b1  = (const float*)d_in[3];
    const float* w2  = (const float*)d_in[4];
    const float* b2  = (const float*)d_in[5];
    float* out = (float*)d_out;

    char* ws = (char*)d_ws;
    size_t off = 0;
    auto alloc = [&](size_t bytes) -> void* {
        void* p = ws + off;
        off += (bytes + 255) & ~(size_t)255;
        return p;
    };
    float* invH = (float*)alloc((size_t)BB * LL * 4);
    float* invP = (float*)alloc((size_t)BB * LL * 4);
    float* pVal = (float*)alloc((size_t)BB * LL * NSPLIT * 4);
    int*   pArg = (int*)  alloc((size_t)BB * LL * NSPLIT * 4);
    float* Sv   = (float*)alloc((size_t)BB * LL * 4);
    int*   Sa   = (int*)  alloc((size_t)BB * LL * 4);
    float* T    = (float*)alloc((size_t)BB * CC * LL * 4);
    float* hbuf = (float*)alloc((size_t)BB * CC * LL * 4);

    prep_kernel<<<dim3((BB * LL + 255) / 256), 256, 0, stream>>>(HSI, PAN, invH, invP);
    sim_kernel<<<dim3(LL / TM, NSPLIT, BB), 256, 0, stream>>>(HSI, PAN, invP, pVal, pArg);
    merge_kernel<<<dim3((BB * LL + 255) / 256), 256, 0, stream>>>(pVal, pArg, invH, Sv, Sa);
    tfold_kernel<<<dim3((BB * CC * LL + 255) / 256), 256, 0, stream>>>(PAN, Sa, T);
    conv1_kernel<<<dim3(BB * LL / 256, CC / COG), 256, 0, stream>>>(T, HSI, w1, b1, hbuf);
    conv2_kernel<<<dim3(BB * LL / 256, CC / COG), 256, 0, stream>>>(hbuf, HSI, Sv, w2, b2, out);
}

// Round 2
// 501.347 us; speedup vs baseline: 2.9847x; 2.9847x over previous
//
#include <hip/hip_runtime.h>
#include <hip/hip_bf16.h>
#include <stdint.h>

#define HH 80
#define WW 80
#define LL 6400
#define CC 32
#define BB 2
#define COG 8
#define DELTA 3e-4f

typedef __bf16 bf16x8 __attribute__((ext_vector_type(8)));
typedef float  f32x4  __attribute__((ext_vector_type(4)));

__device__ __forceinline__ int div80(int v) {
    return (int)(((unsigned)v * 52429u) >> 22);   // exact for 0 <= v < 52428
}

__device__ __forceinline__ unsigned short f2bf(float f) {
    unsigned int u = __float_as_uint(f);
    return (unsigned short)((u + 0x7fffu + ((u >> 16) & 1u)) >> 16);   // RNE
}
__device__ __forceinline__ float bf2f(unsigned short s) {
    return __uint_as_float(((unsigned int)s) << 16);
}

__device__ __forceinline__ void gload_lds16(void* g, void* l) {
    __builtin_amdgcn_global_load_lds(
        (__attribute__((address_space(1))) void*)g,
        (__attribute__((address_space(3))) void*)l, 16, 0, 0);
}

// ---------------- prep: inverse column norms of unfold(HSI), unfold(PAN) ----------------
__global__ void prep_kernel(const float* __restrict__ HSI, const float* __restrict__ PAN,
                            float* __restrict__ invH, float* __restrict__ invP) {
    int g = blockIdx.x * blockDim.x + threadIdx.x;
    if (g >= BB * LL) return;
    int b = g / LL, l = g - b * LL;
    int y = div80(l), x = l - y * 80;
    const float* Hb = HSI + (size_t)b * CC * LL;
    const float* Pb = PAN + (size_t)b * CC * LL;
    float sh = 0.f, sp = 0.f;
    for (int c = 0; c < CC; ++c) {
        const float* hc = Hb + c * LL;
        const float* pc = Pb + c * LL;
        #pragma unroll
        for (int i = 0; i < 3; ++i) {
            int yy = y + i - 1;
            if ((unsigned)yy >= 80u) continue;
            #pragma unroll
            for (int j = 0; j < 3; ++j) {
                int xx = x + j - 1;
                if ((unsigned)xx >= 80u) continue;
                float hv = hc[yy * 80 + xx]; sh = fmaf(hv, hv, sh);
                float pv = pc[yy * 80 + xx]; sp = fmaf(pv, pv, sp);
            }
        }
    }
    invH[g] = 1.f / fmaxf(sqrtf(sh), 1e-12f);
    invP[g] = 1.f / fmaxf(sqrtf(sp), 1e-12f);
}

// ---------------- pack: normalized unfold columns -> split-bf16, swizzled rows ----------------
// Layout: pack[b][phys(6)][row(6400)][256 B]; phys 0..2 = hi of k in [96q,96q+96), 3..5 = lo.
// Within a row, data granule g (16 B = 8 bf16) sits at slot (g ^ (row & 15)).
__global__ void pack_kernel(const float* __restrict__ HSI, const float* __restrict__ PAN,
                            const float* __restrict__ invH, const float* __restrict__ invP,
                            char* __restrict__ Apack, char* __restrict__ Bpack) {
    int t = blockIdx.x * 256 + threadIdx.x;
    if (t >= BB * 2 * LL * 36) return;
    int g = t % 36;
    int rest = t / 36;
    int l = rest % LL; rest /= LL;
    int mat = rest & 1;      // 0 = PAN (A operand), 1 = HSI (B operand)
    int b = rest >> 1;
    const float* img = (mat ? HSI : PAN) + (size_t)b * CC * LL;
    float inv = (mat ? invH : invP)[b * LL + l];
    int y = div80(l), x = l - y * 80;
    int k0 = g * 8;
    int c = k0 / 9, tap = k0 - c * 9;
    unsigned short hs[8], ls[8];
    #pragma unroll
    for (int j = 0; j < 8; ++j) {
        int t3 = tap / 3;
        int dy = t3 - 1, dx = tap - t3 * 3 - 1;
        int yy = y + dy, xx = x + dx;
        float val = ((unsigned)yy < 80u && (unsigned)xx < 80u)
                        ? img[(size_t)c * LL + yy * 80 + xx] * inv : 0.f;
        unsigned short hi = f2bf(val);
        hs[j] = hi;
        ls[j] = f2bf(val - bf2f(hi));
        if (++tap == 9) { tap = 0; ++c; }
    }
    char* pk = mat ? Bpack : Apack;
    int slot = (g % 12) ^ (l & 15);
    int q = g / 12;
    size_t off_hi = ((size_t)(b * 6 + q) * LL + l) * 256 + slot * 16;
    size_t off_lo = ((size_t)(b * 6 + 3 + q) * LL + l) * 256 + slot * 16;
    uint4 hv, lv;
    hv.x = hs[0] | ((unsigned)hs[1] << 16); hv.y = hs[2] | ((unsigned)hs[3] << 16);
    hv.z = hs[4] | ((unsigned)hs[5] << 16); hv.w = hs[6] | ((unsigned)hs[7] << 16);
    lv.x = ls[0] | ((unsigned)ls[1] << 16); lv.y = ls[2] | ((unsigned)ls[3] << 16);
    lv.z = ls[4] | ((unsigned)ls[5] << 16); lv.w = ls[6] | ((unsigned)ls[7] << 16);
    *(uint4*)(pk + off_hi) = hv;
    *(uint4*)(pk + off_lo) = lv;
}

// ---------------- simq: MFMA similarity, per-(64l-tile, m) max -> tileMax ----------------
// Logical K'' = 864: chunks 0..8 of 96; A planes (hi,hi,lo), B planes (hi,lo,hi).
// Block: 128 l x 128 m, 4 waves (2l x 2m), wave tile 64x64, mfma_f32_16x16x32_bf16.
__global__ __launch_bounds__(256) void simq_kernel(const char* __restrict__ Apack,
                                                   const char* __restrict__ Bpack,
                                                   float* __restrict__ tileMax) {
    __shared__ __align__(16) char Alds[32768];
    __shared__ __align__(16) char Blds[32768];
    const int mt = blockIdx.x, sp = blockIdx.y, b = blockIdx.z;
    const int tid = threadIdx.x;
    const int lane = tid & 63, w = tid >> 6;
    const int wl = w >> 1, wm = w & 1;
    const int r15 = lane & 15, h = lane >> 4;
    const char* Ab = Apack + (size_t)b * 6 * LL * 256;
    const char* Bb = Bpack + (size_t)b * 6 * LL * 256;
    const int m0 = mt * 128;
    const f32x4 fzero = {0.f, 0.f, 0.f, 0.f};

    #pragma unroll 1
    for (int lt = 0; lt < 10; ++lt) {
        const int l0 = (sp * 10 + lt) * 128;
        f32x4 acc[4][4];
        #pragma unroll
        for (int i = 0; i < 4; ++i)
            #pragma unroll
            for (int j = 0; j < 4; ++j) acc[i][j] = fzero;

        #pragma unroll 1
        for (int c = 0; c < 9; ++c) {
            const int pA = (c < 6) ? (c % 3) : (c - 3);
            const int pB = (c < 6) ? c : (c - 6);
            __syncthreads();
            const char* gA = Ab + ((size_t)pA * LL + l0) * 256 + w * 8192 + lane * 16;
            const char* gB = Bb + ((size_t)pB * LL + m0) * 256 + w * 8192 + lane * 16;
            char* lA = Alds + w * 8192;
            char* lB = Blds + w * 8192;
            #pragma unroll
            for (int i = 0; i < 8; ++i) {
                gload_lds16((void*)(gA + i * 1024), lA + i * 1024);
                gload_lds16((void*)(gB + i * 1024), lB + i * 1024);
            }
            __syncthreads();
            #pragma unroll
            for (int ks = 0; ks < 3; ++ks) {
                const int gp = ((ks * 4 + h) ^ r15) * 16;
                bf16x8 af[4], bfr[4];
                #pragma unroll
                for (int f = 0; f < 4; ++f) {
                    af[f]  = *(const bf16x8*)(Alds + (wl * 64 + f * 16 + r15) * 256 + gp);
                    bfr[f] = *(const bf16x8*)(Blds + (wm * 64 + f * 16 + r15) * 256 + gp);
                }
                #pragma unroll
                for (int fl = 0; fl < 4; ++fl)
                    #pragma unroll
                    for (int fm = 0; fm < 4; ++fm)
                        acc[fl][fm] = __builtin_amdgcn_mfma_f32_16x16x32_bf16(
                            af[fl], bfr[fm], acc[fl][fm], 0, 0, 0);
            }
        }
        // fold: per m-col max over the wave's 64 l rows
        const int T = (sp * 10 + lt) * 2 + wl;
        #pragma unroll
        for (int fm = 0; fm < 4; ++fm) {
            float v = -3.0e38f;
            #pragma unroll
            for (int fl = 0; fl < 4; ++fl) {
                f32x4 a = acc[fl][fm];
                v = fmaxf(v, fmaxf(fmaxf(a[0], a[1]), fmaxf(a[2], a[3])));
            }
            v = fmaxf(v, __shfl_xor(v, 16, 64));
            v = fmaxf(v, __shfl_xor(v, 32, 64));
            if (h == 0) {
                const int m = m0 + wm * 64 + fm * 16 + r15;
                tileMax[((size_t)b * 100 + T) * LL + m] = v;
            }
        }
    }
}

// ---------------- argfix: exact fp32 rescore of candidate tiles -> exact S, argmax ----------------
__global__ __launch_bounds__(256) void argfix_kernel(const float* __restrict__ HSI,
                                                     const float* __restrict__ PAN,
                                                     const float* __restrict__ invH,
                                                     const float* __restrict__ invP,
                                                     const float* __restrict__ tileMax,
                                                     float* __restrict__ Sv, int* __restrict__ Sa) {
    const int m = blockIdx.x, b = blockIdx.y, tid = threadIdx.x;
    __shared__ float smax[100];
    __shared__ float scol[288];
    __shared__ float sred[256];
    __shared__ float rbv;
    __shared__ int   rbl;
    if (tid < 100) smax[tid] = tileMax[((size_t)b * 100 + tid) * LL + m];
    {
        int ym = div80(m), xm = m - ym * 80;
        for (int idx = tid; idx < 288; idx += 256) {
            int c = idx / 9, tap = idx - c * 9;
            int t3 = tap / 3;
            int yy = ym + t3 - 1, xx = xm + (tap - t3 * 3) - 1;
            scol[idx] = ((unsigned)yy < 80u && (unsigned)xx < 80u)
                            ? HSI[((size_t)b * CC + c) * LL + yy * 80 + xx] : 0.f;
        }
    }
    if (tid == 0) { rbv = -3.0e38f; rbl = 0x7fffffff; }
    __syncthreads();
    float v1 = -3.0e38f;
    for (int t = 0; t < 100; ++t) v1 = fmaxf(v1, smax[t]);
    const float th = v1 - DELTA;
    const float ihm = invH[b * LL + m];
    const int ll = tid & 63, kq = tid >> 6;
    for (int T = 0; T < 100; ++T) {
        if (smax[T] < th) continue;
        const int l = T * 64 + ll;
        const int y = div80(l), x = l - y * 80;
        float part = 0.f;
        int k = kq * 72;
        int c = k / 9, tap = k - c * 9;
        for (int i = 0; i < 72; ++i) {
            int t3 = tap / 3;
            int yy = y + t3 - 1, xx = x + (tap - t3 * 3) - 1;
            float av = ((unsigned)yy < 80u && (unsigned)xx < 80u)
                           ? PAN[((size_t)b * CC + c) * LL + yy * 80 + xx] : 0.f;
            part = fmaf(av, scol[k + i], part);
            if (++tap == 9) { tap = 0; ++c; }
        }
        sred[tid] = part;
        __syncthreads();
        if (tid < 64) {
            float val = (sred[tid] + sred[tid + 64] + sred[tid + 128] + sred[tid + 192])
                        * invP[b * LL + l] * ihm;
            sred[tid] = val;
        }
        __syncthreads();
        if (tid == 0) {
            float bv = rbv; int bl = rbl;
            for (int i2 = 0; i2 < 64; ++i2) {
                float v = sred[i2];
                if (v > bv) { bv = v; bl = T * 64 + i2; }
            }
            rbv = bv; rbl = bl;
        }
        __syncthreads();
    }
    if (tid == 0) { Sv[b * LL + m] = rbv; Sa[b * LL + m] = rbl; }
}

// ---------------- T_lv3 = fold3x3(gathered PAN patches) / 9 ----------------
__global__ void tfold_kernel(const float* __restrict__ PAN, const int* __restrict__ Sa,
                             float* __restrict__ T) {
    int g = blockIdx.x * blockDim.x + threadIdx.x;
    if (g >= BB * CC * LL) return;
    int bc = g / LL, l = g - bc * LL;
    int b = bc >> 5;
    int y = div80(l), x = l - y * 80;
    const float* img = PAN + (size_t)bc * LL;
    const int* Sab = Sa + b * LL;
    float acc = 0.f;
    #pragma unroll
    for (int i = 0; i < 3; ++i) {
        int yp = y + 1 - i;
        if ((unsigned)yp >= 80u) continue;
        #pragma unroll
        for (int j = 0; j < 3; ++j) {
            int xp = x + 1 - j;
            if ((unsigned)xp >= 80u) continue;
            int a = Sab[yp * 80 + xp];
            int ya = div80(a), xa = a - ya * 80;
            int py = ya + i - 1, px = xa + j - 1;
            if ((unsigned)py < 80u && (unsigned)px < 80u) acc += img[py * 80 + px];
        }
    }
    T[g] = acc * (1.f / 9.f);
}

// ---------------- conv1: h = relu(conv3x3(concat(T,HSI), w1) + b1) ----------------
__global__ __launch_bounds__(256) void conv1_kernel(const float* __restrict__ T,
                                                    const float* __restrict__ HSI,
                                                    const float* __restrict__ w1,
                                                    const float* __restrict__ b1,
                                                    float* __restrict__ h) {
    __shared__ __align__(16) float wl[64][9][COG];
    const int tid = threadIdx.x;
    const int co0 = blockIdx.y * COG;
    for (int idx = tid; idx < 64 * 9 * COG; idx += 256) {
        int cog = idx & (COG - 1);
        int rest = idx >> 3;
        int cin = rest / 9, tap = rest - cin * 9;
        wl[cin][tap][cog] = w1[(co0 + cog) * (64 * 9) + cin * 9 + tap];
    }
    __syncthreads();
    const int g = blockIdx.x * 256 + tid;
    const int b = g / LL, l = g - b * LL;
    const int y = div80(l), x = l - y * 80;
    float acc[COG];
    #pragma unroll
    for (int i = 0; i < COG; ++i) acc[i] = 0.f;
    for (int cin = 0; cin < 64; ++cin) {
        const float* img = (cin < CC) ? (T + (size_t)(b * CC + cin) * LL)
                                      : (HSI + (size_t)(b * CC + (cin - CC)) * LL);
        float tap[9];
        #pragma unroll
        for (int i = 0; i < 3; ++i)
            #pragma unroll
            for (int j = 0; j < 3; ++j) {
                int yy = y + i - 1, xx = x + j - 1;
                tap[i * 3 + j] = ((unsigned)yy < 80u && (unsigned)xx < 80u) ? img[yy * 80 + xx] : 0.f;
            }
        #pragma unroll
        for (int t9 = 0; t9 < 9; ++t9) {
            const float4 wa = *reinterpret_cast<const float4*>(&wl[cin][t9][0]);
            const float4 wb = *reinterpret_cast<const float4*>(&wl[cin][t9][4]);
            acc[0] = fmaf(tap[t9], wa.x, acc[0]);
            acc[1] = fmaf(tap[t9], wa.y, acc[1]);
            acc[2] = fmaf(tap[t9], wa.z, acc[2]);
            acc[3] = fmaf(tap[t9], wa.w, acc[3]);
            acc[4] = fmaf(tap[t9], wb.x, acc[4]);
            acc[5] = fmaf(tap[t9], wb.y, acc[5]);
            acc[6] = fmaf(tap[t9], wb.z, acc[6]);
            acc[7] = fmaf(tap[t9], wb.w, acc[7]);
        }
    }
    #pragma unroll
    for (int cog = 0; cog < COG; ++cog) {
        float v = acc[cog] + b1[co0 + cog];
        h[(size_t)(b * CC + co0 + cog) * LL + l] = fmaxf(v, 0.f);
    }
}

// ---------------- conv2: out = (conv3x3(h, w2) + b2) * S + HSI ----------------
__global__ __launch_bounds__(256) void conv2_kernel(const float* __restrict__ hbuf,
                                                    const float* __restrict__ HSI,
                                                    const float* __restrict__ Sv,
                                                    const float* __restrict__ w2,
                                                    const float* __restrict__ b2,
                                                    float* __restrict__ out) {
    __shared__ __align__(16) float wl[CC][9][COG];
    const int tid = threadIdx.x;
    const int co0 = blockIdx.y * COG;
    for (int idx = tid; idx < CC * 9 * COG; idx += 256) {
        int cog = idx & (COG - 1);
        int rest = idx >> 3;
        int cin = rest / 9, tap = rest - cin * 9;
        wl[cin][tap][cog] = w2[(co0 + cog) * (CC * 9) + cin * 9 + tap];
    }
    __syncthreads();
    const int g = blockIdx.x * 256 + tid;
    const int b = g / LL, l = g - b * LL;
    const int y = div80(l), x = l - y * 80;
    float acc[COG];
    #pragma unroll
    for (int i = 0; i < COG; ++i) acc[i] = 0.f;
    for (int cin = 0; cin < CC; ++cin) {
        const float* img = hbuf + (size_t)(b * CC + cin) * LL;
        float tap[9];
        #pragma unroll
        for (int i = 0; i < 3; ++i)
            #pragma unroll
            for (int j = 0; j < 3; ++j) {
                int yy = y + i - 1, xx = x + j - 1;
                tap[i * 3 + j] = ((unsigned)yy < 80u && (unsigned)xx < 80u) ? img[yy * 80 + xx] : 0.f;
            }
        #pragma unroll
        for (int t9 = 0; t9 < 9; ++t9) {
            const float4 wa = *reinterpret_cast<const float4*>(&wl[cin][t9][0]);
            const float4 wb = *reinterpret_cast<const float4*>(&wl[cin][t9][4]);
            acc[0] = fmaf(tap[t9], wa.x, acc[0]);
            acc[1] = fmaf(tap[t9], wa.y, acc[1]);
            acc[2] = fmaf(tap[t9], wa.z, acc[2]);
            acc[3] = fmaf(tap[t9], wa.w, acc[3]);
            acc[4] = fmaf(tap[t9], wb.x, acc[4]);
            acc[5] = fmaf(tap[t9], wb.y, acc[5]);
            acc[6] = fmaf(tap[t9], wb.z, acc[6]);
            acc[7] = fmaf(tap[t9], wb.w, acc[7]);
        }
    }
    const float s = Sv[b * LL + l];
    #pragma unroll
    for (int cog = 0; cog < COG; ++cog) {
        int c = co0 + cog;
        out[(size_t)(b * CC + c) * LL + l] = fmaf(acc[cog] + b2[c], s, HSI[(size_t)(b * CC + c) * LL + l]);
    }
}

extern "C" void kernel_launch(void* const* d_in, const int* in_sizes, int n_in,
                              void* d_out, int out_size, void* d_ws, size_t ws_size,
                              hipStream_t stream) {
    const float* HSI = (const float*)d_in[0];
    const float* PAN = (const float*)d_in[1];
    const float* w1  = (const float*)d_in[2];
    const float* b1  = (const float*)d_in[3];
    const float* w2  = (const float*)d_in[4];
    const float* b2  = (const float*)d_in[5];
    float* out = (float*)d_out;

    char* ws = (char*)d_ws;
    size_t off = 0;
    auto alloc = [&](size_t bytes) -> void* {
        void* p = ws + off;
        off += (bytes + 255) & ~(size_t)255;
        return p;
    };
    float* invH  = (float*)alloc((size_t)BB * LL * 4);
    float* invP  = (float*)alloc((size_t)BB * LL * 4);
    char*  Apack = (char*) alloc((size_t)BB * 6 * LL * 256);   // 19.66 MB
    char*  Bpack = (char*) alloc((size_t)BB * 6 * LL * 256);   // 19.66 MB
    float* tileMax = (float*)alloc((size_t)BB * 100 * LL * 4); // 5.12 MB
    float* Sv    = (float*)alloc((size_t)BB * LL * 4);
    int*   Sa    = (int*)  alloc((size_t)BB * LL * 4);
    float* T     = (float*)alloc((size_t)BB * CC * LL * 4);
    float* hbuf  = (float*)alloc((size_t)BB * CC * LL * 4);

    prep_kernel<<<dim3((BB * LL + 255) / 256), 256, 0, stream>>>(HSI, PAN, invH, invP);
    pack_kernel<<<dim3((BB * 2 * LL * 36 + 255) / 256), 256, 0, stream>>>(HSI, PAN, invH, invP, Apack, Bpack);
    simq_kernel<<<dim3(LL / 128, 5, BB), 256, 0, stream>>>(Apack, Bpack, tileMax);
    argfix_kernel<<<dim3(LL, BB), 256, 0, stream>>>(HSI, PAN, invH, invP, tileMax, Sv, Sa);
    tfold_kernel<<<dim3((BB * CC * LL + 255) / 256), 256, 0, stream>>>(PAN, Sa, T);
    conv1_kernel<<<dim3(BB * LL / 256, CC / COG), 256, 0, stream>>>(T, HSI, w1, b1, hbuf);
    conv2_kernel<<<dim3(BB * LL / 256, CC / COG), 256, 0, stream>>>(hbuf, HSI, Sv, w2, b2, out);
}

// Round 3
// 472.267 us; speedup vs baseline: 3.1684x; 1.0616x over previous
//
#include <hip/hip_runtime.h>
#include <hip/hip_bf16.h>
#include <stdint.h>

#define HH 80
#define WW 80
#define LL 6400
#define CC 32
#define BB 2
#define COG 8
#define DELTA 0.01f

typedef __bf16 bf16x8 __attribute__((ext_vector_type(8)));
typedef float  f32x4  __attribute__((ext_vector_type(4)));

__device__ __forceinline__ int div80(int v) {
    return (int)(((unsigned)v * 52429u) >> 22);   // exact for 0 <= v < 52428
}

__device__ __forceinline__ unsigned short f2bf(float f) {
    unsigned int u = __float_as_uint(f);
    return (unsigned short)((u + 0x7fffu + ((u >> 16) & 1u)) >> 16);   // RNE
}

__device__ __forceinline__ void gload_lds16(void* g, void* l) {
    __builtin_amdgcn_global_load_lds(
        (__attribute__((address_space(1))) void*)g,
        (__attribute__((address_space(3))) void*)l, 16, 0, 0);
}

// ---------------- prep1: per-(b,c,l) 3x3 squared-sums ----------------
__global__ void prep1_kernel(const float* __restrict__ HSI, const float* __restrict__ PAN,
                             float* __restrict__ partH, float* __restrict__ partP) {
    int g = blockIdx.x * 256 + threadIdx.x;          // (b*CC + c)*LL + l
    if (g >= BB * CC * LL) return;
    int l = g % LL;
    int bc = g / LL;
    int y = div80(l), x = l - y * 80;
    const float* hc = HSI + (size_t)bc * LL;
    const float* pc = PAN + (size_t)bc * LL;
    float sh = 0.f, sp = 0.f;
    #pragma unroll
    for (int i = 0; i < 3; ++i) {
        int yy = y + i - 1;
        if ((unsigned)yy >= 80u) continue;
        #pragma unroll
        for (int j = 0; j < 3; ++j) {
            int xx = x + j - 1;
            if ((unsigned)xx >= 80u) continue;
            float hv = hc[yy * 80 + xx]; sh = fmaf(hv, hv, sh);
            float pv = pc[yy * 80 + xx]; sp = fmaf(pv, pv, sp);
        }
    }
    partH[g] = sh;
    partP[g] = sp;
}

// ---------------- prep2: reduce over channels -> inverse norms ----------------
__global__ void prep2_kernel(const float* __restrict__ partH, const float* __restrict__ partP,
                             float* __restrict__ invH, float* __restrict__ invP) {
    int g = blockIdx.x * 256 + threadIdx.x;          // b*LL + l
    if (g >= BB * LL) return;
    int b = g / LL, l = g - b * LL;
    float sh = 0.f, sp = 0.f;
    #pragma unroll
    for (int c = 0; c < CC; ++c) {
        sh += partH[((size_t)(b * CC + c)) * LL + l];
        sp += partP[((size_t)(b * CC + c)) * LL + l];
    }
    invH[g] = 1.f / fmaxf(sqrtf(sh), 1e-12f);
    invP[g] = 1.f / fmaxf(sqrtf(sp), 1e-12f);
}

// ---------------- pack: normalized unfold columns -> bf16 (hi only), swizzled rows ----------------
// Layout: pack[b][plane(3)][row(6400)][256 B]; plane q = k in [96q, 96q+96).
// Within a row, data granule g (16 B = 8 bf16) sits at slot ((g%12) ^ (row & 15)).
__global__ void pack_kernel(const float* __restrict__ HSI, const float* __restrict__ PAN,
                            const float* __restrict__ invH, const float* __restrict__ invP,
                            char* __restrict__ Apack, char* __restrict__ Bpack) {
    int t = blockIdx.x * 256 + threadIdx.x;
    if (t >= BB * 2 * LL * 36) return;
    int g = t % 36;
    int rest = t / 36;
    int l = rest % LL; rest /= LL;
    int mat = rest & 1;      // 0 = PAN (A operand), 1 = HSI (B operand)
    int b = rest >> 1;
    const float* img = (mat ? HSI : PAN) + (size_t)b * CC * LL;
    float inv = (mat ? invH : invP)[b * LL + l];
    int y = div80(l), x = l - y * 80;
    int k0 = g * 8;
    int c = k0 / 9, tap = k0 - c * 9;
    unsigned short hs[8];
    #pragma unroll
    for (int j = 0; j < 8; ++j) {
        int t3 = tap / 3;
        int dy = t3 - 1, dx = tap - t3 * 3 - 1;
        int yy = y + dy, xx = x + dx;
        float val = ((unsigned)yy < 80u && (unsigned)xx < 80u)
                        ? img[(size_t)c * LL + yy * 80 + xx] * inv : 0.f;
        hs[j] = f2bf(val);
        if (++tap == 9) { tap = 0; ++c; }
    }
    char* pk = mat ? Bpack : Apack;
    int slot = (g % 12) ^ (l & 15);
    int q = g / 12;
    size_t off = ((size_t)(b * 3 + q) * LL + l) * 256 + slot * 16;
    uint4 hv;
    hv.x = hs[0] | ((unsigned)hs[1] << 16); hv.y = hs[2] | ((unsigned)hs[3] << 16);
    hv.z = hs[4] | ((unsigned)hs[5] << 16); hv.w = hs[6] | ((unsigned)hs[7] << 16);
    *(uint4*)(pk + off) = hv;
}

// ---------------- simq: MFMA similarity (hi-only, K=288), per-(64l-tile, m) max ----------------
// Block: 128 l x 128 m, 4 waves (2l x 2m), wave tile 64x64, mfma_f32_16x16x32_bf16.
// 1D grid of 500 with bijective XCD swizzle; consecutive wg share one (b,sp) A panel.
__global__ __launch_bounds__(256) void simq_kernel(const char* __restrict__ Apack,
                                                   const char* __restrict__ Bpack,
                                                   float* __restrict__ tileMax) {
    __shared__ __align__(16) char Alds[32768];
    __shared__ __align__(16) char Blds[32768];
    // bijective XCD swizzle for nwg=500: q=62, r=4
    const int orig = blockIdx.x;
    const int xcd = orig & 7, idx = orig >> 3;
    const int wg = (xcd < 4 ? xcd * 63 : 252 + (xcd - 4) * 62) + idx;
    const int b = wg / 250;
    int rest = wg - b * 250;
    const int sp = rest / 50;
    const int mt = rest - sp * 50;

    const int tid = threadIdx.x;
    const int lane = tid & 63, w = tid >> 6;
    const int wl = w >> 1, wm = w & 1;
    const int r15 = lane & 15, h = lane >> 4;
    const char* Ab = Apack + (size_t)b * 3 * LL * 256;
    const char* Bb = Bpack + (size_t)b * 3 * LL * 256;
    const int m0 = mt * 128;
    const f32x4 fzero = {0.f, 0.f, 0.f, 0.f};

    #pragma unroll 1
    for (int lt = 0; lt < 10; ++lt) {
        const int l0 = (sp * 10 + lt) * 128;
        f32x4 acc[4][4];
        #pragma unroll
        for (int i = 0; i < 4; ++i)
            #pragma unroll
            for (int j = 0; j < 4; ++j) acc[i][j] = fzero;

        #pragma unroll 1
        for (int c = 0; c < 3; ++c) {
            __syncthreads();
            const char* gA = Ab + ((size_t)c * LL + l0) * 256 + w * 8192 + lane * 16;
            const char* gB = Bb + ((size_t)c * LL + m0) * 256 + w * 8192 + lane * 16;
            char* lA = Alds + w * 8192;
            char* lB = Blds + w * 8192;
            #pragma unroll
            for (int i = 0; i < 8; ++i) {
                gload_lds16((void*)(gA + i * 1024), lA + i * 1024);
                gload_lds16((void*)(gB + i * 1024), lB + i * 1024);
            }
            __syncthreads();
            #pragma unroll
            for (int ks = 0; ks < 3; ++ks) {
                const int gp = ((ks * 4 + h) ^ r15) * 16;
                bf16x8 af[4], bfr[4];
                #pragma unroll
                for (int f = 0; f < 4; ++f) {
                    af[f]  = *(const bf16x8*)(Alds + (wl * 64 + f * 16 + r15) * 256 + gp);
                    bfr[f] = *(const bf16x8*)(Blds + (wm * 64 + f * 16 + r15) * 256 + gp);
                }
                #pragma unroll
                for (int fl = 0; fl < 4; ++fl)
                    #pragma unroll
                    for (int fm = 0; fm < 4; ++fm)
                        acc[fl][fm] = __builtin_amdgcn_mfma_f32_16x16x32_bf16(
                            af[fl], bfr[fm], acc[fl][fm], 0, 0, 0);
            }
        }
        // fold: per m-col max over the wave's 64 l rows
        const int T = (sp * 10 + lt) * 2 + wl;
        #pragma unroll
        for (int fm = 0; fm < 4; ++fm) {
            float v = -3.0e38f;
            #pragma unroll
            for (int fl = 0; fl < 4; ++fl) {
                f32x4 a = acc[fl][fm];
                v = fmaxf(v, fmaxf(fmaxf(a[0], a[1]), fmaxf(a[2], a[3])));
            }
            v = fmaxf(v, __shfl_xor(v, 16, 64));
            v = fmaxf(v, __shfl_xor(v, 32, 64));
            if (h == 0) {
                const int m = m0 + wm * 64 + fm * 16 + r15;
                tileMax[((size_t)b * 100 + T) * LL + m] = v;
            }
        }
    }
}

// ---------------- argfix: exact fp32 rescore of candidate tiles -> exact S, argmax ----------------
__global__ __launch_bounds__(256) void argfix_kernel(const float* __restrict__ HSI,
                                                     const float* __restrict__ PAN,
                                                     const float* __restrict__ invH,
                                                     const float* __restrict__ invP,
                                                     const float* __restrict__ tileMax,
                                                     float* __restrict__ Sv, int* __restrict__ Sa) {
    const int m = blockIdx.x, b = blockIdx.y, tid = threadIdx.x;
    __shared__ float smax[100];
    __shared__ float scol[288];
    __shared__ float sred[256];
    __shared__ float rbv;
    __shared__ int   rbl;
    if (tid < 100) smax[tid] = tileMax[((size_t)b * 100 + tid) * LL + m];
    {
        int ym = div80(m), xm = m - ym * 80;
        for (int idx = tid; idx < 288; idx += 256) {
            int c = idx / 9, tap = idx - c * 9;
            int t3 = tap / 3;
            int yy = ym + t3 - 1, xx = xm + (tap - t3 * 3) - 1;
            scol[idx] = ((unsigned)yy < 80u && (unsigned)xx < 80u)
                            ? HSI[((size_t)b * CC + c) * LL + yy * 80 + xx] : 0.f;
        }
    }
    if (tid == 0) { rbv = -3.0e38f; rbl = 0x7fffffff; }
    __syncthreads();
    float v1 = -3.0e38f;
    for (int t = 0; t < 100; ++t) v1 = fmaxf(v1, smax[t]);
    const float th = v1 - DELTA;
    const float ihm = invH[b * LL + m];
    const int ll = tid & 63, kq = tid >> 6;
    for (int T = 0; T < 100; ++T) {
        if (smax[T] < th) continue;
        const int l = T * 64 + ll;
        const int y = div80(l), x = l - y * 80;
        float part = 0.f;
        int k = kq * 72;
        int c = k / 9, tap = k - c * 9;
        for (int i = 0; i < 72; ++i) {
            int t3 = tap / 3;
            int yy = y + t3 - 1, xx = x + (tap - t3 * 3) - 1;
            float av = ((unsigned)yy < 80u && (unsigned)xx < 80u)
                           ? PAN[((size_t)b * CC + c) * LL + yy * 80 + xx] : 0.f;
            part = fmaf(av, scol[k + i], part);
            if (++tap == 9) { tap = 0; ++c; }
        }
        sred[tid] = part;
        __syncthreads();
        if (tid < 64) {
            float v = (sred[tid] + sred[tid + 64] + sred[tid + 128] + sred[tid + 192])
                      * invP[b * LL + l] * ihm;
            int li = T * 64 + tid;
            #pragma unroll
            for (int d = 1; d < 64; d <<= 1) {
                float ov = __shfl_xor(v, d, 64);
                int   ol = __shfl_xor(li, d, 64);
                if (ov > v || (ov == v && ol < li)) { v = ov; li = ol; }
            }
            if (tid == 0) {
                if (v > rbv || (v == rbv && li < rbl)) { rbv = v; rbl = li; }
            }
        }
        __syncthreads();
    }
    if (tid == 0) { Sv[b * LL + m] = rbv; Sa[b * LL + m] = rbl; }
}

// ---------------- T_lv3 = fold3x3(gathered PAN patches) / 9 ----------------
__global__ void tfold_kernel(const float* __restrict__ PAN, const int* __restrict__ Sa,
                             float* __restrict__ T) {
    int g = blockIdx.x * blockDim.x + threadIdx.x;
    if (g >= BB * CC * LL) return;
    int bc = g / LL, l = g - bc * LL;
    int b = bc >> 5;
    int y = div80(l), x = l - y * 80;
    const float* img = PAN + (size_t)bc * LL;
    const int* Sab = Sa + b * LL;
    float acc = 0.f;
    #pragma unroll
    for (int i = 0; i < 3; ++i) {
        int yp = y + 1 - i;
        if ((unsigned)yp >= 80u) continue;
        #pragma unroll
        for (int j = 0; j < 3; ++j) {
            int xp = x + 1 - j;
            if ((unsigned)xp >= 80u) continue;
            int a = Sab[yp * 80 + xp];
            int ya = div80(a), xa = a - ya * 80;
            int py = ya + i - 1, px = xa + j - 1;
            if ((unsigned)py < 80u && (unsigned)px < 80u) acc += img[py * 80 + px];
        }
    }
    T[g] = acc * (1.f / 9.f);
}

// ---------------- conv1: h = relu(conv3x3(concat(T,HSI), w1) + b1) ----------------
__global__ __launch_bounds__(256) void conv1_kernel(const float* __restrict__ T,
                                                    const float* __restrict__ HSI,
                                                    const float* __restrict__ w1,
                                                    const float* __restrict__ b1,
                                                    float* __restrict__ h) {
    __shared__ __align__(16) float wl[64][9][COG];
    const int tid = threadIdx.x;
    const int co0 = blockIdx.y * COG;
    for (int idx = tid; idx < 64 * 9 * COG; idx += 256) {
        int cog = idx & (COG - 1);
        int rest = idx >> 3;
        int cin = rest / 9, tap = rest - cin * 9;
        wl[cin][tap][cog] = w1[(co0 + cog) * (64 * 9) + cin * 9 + tap];
    }
    __syncthreads();
    const int g = blockIdx.x * 256 + tid;
    const int b = g / LL, l = g - b * LL;
    const int y = div80(l), x = l - y * 80;
    float acc[COG];
    #pragma unroll
    for (int i = 0; i < COG; ++i) acc[i] = 0.f;
    for (int cin = 0; cin < 64; ++cin) {
        const float* img = (cin < CC) ? (T + (size_t)(b * CC + cin) * LL)
                                      : (HSI + (size_t)(b * CC + (cin - CC)) * LL);
        float tap[9];
        #pragma unroll
        for (int i = 0; i < 3; ++i)
            #pragma unroll
            for (int j = 0; j < 3; ++j) {
                int yy = y + i - 1, xx = x + j - 1;
                tap[i * 3 + j] = ((unsigned)yy < 80u && (unsigned)xx < 80u) ? img[yy * 80 + xx] : 0.f;
            }
        #pragma unroll
        for (int t9 = 0; t9 < 9; ++t9) {
            const float4 wa = *reinterpret_cast<const float4*>(&wl[cin][t9][0]);
            const float4 wb = *reinterpret_cast<const float4*>(&wl[cin][t9][4]);
            acc[0] = fmaf(tap[t9], wa.x, acc[0]);
            acc[1] = fmaf(tap[t9], wa.y, acc[1]);
            acc[2] = fmaf(tap[t9], wa.z, acc[2]);
            acc[3] = fmaf(tap[t9], wa.w, acc[3]);
            acc[4] = fmaf(tap[t9], wb.x, acc[4]);
            acc[5] = fmaf(tap[t9], wb.y, acc[5]);
            acc[6] = fmaf(tap[t9], wb.z, acc[6]);
            acc[7] = fmaf(tap[t9], wb.w, acc[7]);
        }
    }
    #pragma unroll
    for (int cog = 0; cog < COG; ++cog) {
        float v = acc[cog] + b1[co0 + cog];
        h[(size_t)(b * CC + co0 + cog) * LL + l] = fmaxf(v, 0.f);
    }
}

// ---------------- conv2: out = (conv3x3(h, w2) + b2) * S + HSI ----------------
__global__ __launch_bounds__(256) void conv2_kernel(const float* __restrict__ hbuf,
                                                    const float* __restrict__ HSI,
                                                    const float* __restrict__ Sv,
                                                    const float* __restrict__ w2,
                                                    const float* __restrict__ b2,
                                                    float* __restrict__ out) {
    __shared__ __align__(16) float wl[CC][9][COG];
    const int tid = threadIdx.x;
    const int co0 = blockIdx.y * COG;
    for (int idx = tid; idx < CC * 9 * COG; idx += 256) {
        int cog = idx & (COG - 1);
        int rest = idx >> 3;
        int cin = rest / 9, tap = rest - cin * 9;
        wl[cin][tap][cog] = w2[(co0 + cog) * (CC * 9) + cin * 9 + tap];
    }
    __syncthreads();
    const int g = blockIdx.x * 256 + tid;
    const int b = g / LL, l = g - b * LL;
    const int y = div80(l), x = l - y * 80;
    float acc[COG];
    #pragma unroll
    for (int i = 0; i < COG; ++i) acc[i] = 0.f;
    for (int cin = 0; cin < CC; ++cin) {
        const float* img = hbuf + (size_t)(b * CC + cin) * LL;
        float tap[9];
        #pragma unroll
        for (int i = 0; i < 3; ++i)
            #pragma unroll
            for (int j = 0; j < 3; ++j) {
                int yy = y + i - 1, xx = x + j - 1;
                tap[i * 3 + j] = ((unsigned)yy < 80u && (unsigned)xx < 80u) ? img[yy * 80 + xx] : 0.f;
            }
        #pragma unroll
        for (int t9 = 0; t9 < 9; ++t9) {
            const float4 wa = *reinterpret_cast<const float4*>(&wl[cin][t9][0]);
            const float4 wb = *reinterpret_cast<const float4*>(&wl[cin][t9][4]);
            acc[0] = fmaf(tap[t9], wa.x, acc[0]);
            acc[1] = fmaf(tap[t9], wa.y, acc[1]);
            acc[2] = fmaf(tap[t9], wa.z, acc[2]);
            acc[3] = fmaf(tap[t9], wa.w, acc[3]);
            acc[4] = fmaf(tap[t9], wb.x, acc[4]);
            acc[5] = fmaf(tap[t9], wb.y, acc[5]);
            acc[6] = fmaf(tap[t9], wb.z, acc[6]);
            acc[7] = fmaf(tap[t9], wb.w, acc[7]);
        }
    }
    const float s = Sv[b * LL + l];
    #pragma unroll
    for (int cog = 0; cog < COG; ++cog) {
        int c = co0 + cog;
        out[(size_t)(b * CC + c) * LL + l] = fmaf(acc[cog] + b2[c], s, HSI[(size_t)(b * CC + c) * LL + l]);
    }
}

extern "C" void kernel_launch(void* const* d_in, const int* in_sizes, int n_in,
                              void* d_out, int out_size, void* d_ws, size_t ws_size,
                              hipStream_t stream) {
    const float* HSI = (const float*)d_in[0];
    const float* PAN = (const float*)d_in[1];
    const float* w1  = (const float*)d_in[2];
    const float* b1  = (const float*)d_in[3];
    const float* w2  = (const float*)d_in[4];
    const float* b2  = (const float*)d_in[5];
    float* out = (float*)d_out;

    char* ws = (char*)d_ws;
    size_t off = 0;
    auto alloc = [&](size_t bytes) -> void* {
        void* p = ws + off;
        off += (bytes + 255) & ~(size_t)255;
        return p;
    };
    float* partH = (float*)alloc((size_t)BB * CC * LL * 4);    // 1.64 MB
    float* partP = (float*)alloc((size_t)BB * CC * LL * 4);    // 1.64 MB
    float* invH  = (float*)alloc((size_t)BB * LL * 4);
    float* invP  = (float*)alloc((size_t)BB * LL * 4);
    char*  Apack = (char*) alloc((size_t)BB * 3 * LL * 256);   // 9.83 MB
    char*  Bpack = (char*) alloc((size_t)BB * 3 * LL * 256);   // 9.83 MB
    float* tileMax = (float*)alloc((size_t)BB * 100 * LL * 4); // 5.12 MB
    float* Sv    = (float*)alloc((size_t)BB * LL * 4);
    int*   Sa    = (int*)  alloc((size_t)BB * LL * 4);
    float* T     = (float*)alloc((size_t)BB * CC * LL * 4);
    float* hbuf  = (float*)alloc((size_t)BB * CC * LL * 4);

    prep1_kernel<<<dim3((BB * CC * LL + 255) / 256), 256, 0, stream>>>(HSI, PAN, partH, partP);
    prep2_kernel<<<dim3((BB * LL + 255) / 256), 256, 0, stream>>>(partH, partP, invH, invP);
    pack_kernel<<<dim3((BB * 2 * LL * 36 + 255) / 256), 256, 0, stream>>>(HSI, PAN, invH, invP, Apack, Bpack);
    simq_kernel<<<dim3(500), 256, 0, stream>>>(Apack, Bpack, tileMax);
    argfix_kernel<<<dim3(LL, BB), 256, 0, stream>>>(HSI, PAN, invH, invP, tileMax, Sv, Sa);
    tfold_kernel<<<dim3((BB * CC * LL + 255) / 256), 256, 0, stream>>>(PAN, Sa, T);
    conv1_kernel<<<dim3(BB * LL / 256, CC / COG), 256, 0, stream>>>(T, HSI, w1, b1, hbuf);
    conv2_kernel<<<dim3(BB * LL / 256, CC / COG), 256, 0, stream>>>(hbuf, HSI, Sv, w2, b2, out);
}

// Round 4
// 332.037 us; speedup vs baseline: 4.5066x; 1.4223x over previous
//
#include <hip/hip_runtime.h>
#include <hip/hip_bf16.h>
#include <stdint.h>

#define HH 80
#define WW 80
#define LL 6400
#define CC 32
#define BB 2
#define COG 8
#define DELTA 0.01f
#define NT16 400

typedef __bf16 bf16x8 __attribute__((ext_vector_type(8)));
typedef float  f32x4  __attribute__((ext_vector_type(4)));

__device__ __forceinline__ int div80(int v) {
    return (int)(((unsigned)v * 52429u) >> 22);   // exact for 0 <= v < 52428
}

__device__ __forceinline__ unsigned short f2bf(float f) {
    unsigned int u = __float_as_uint(f);
    return (unsigned short)((u + 0x7fffu + ((u >> 16) & 1u)) >> 16);   // RNE
}

__device__ __forceinline__ void gload_lds16(void* g, void* l) {
    __builtin_amdgcn_global_load_lds(
        (__attribute__((address_space(1))) void*)g,
        (__attribute__((address_space(3))) void*)l, 16, 0, 0);
}

// ---------------- prep1: per-(b,c,l) 3x3 squared-sums ----------------
__global__ void prep1_kernel(const float* __restrict__ HSI, const float* __restrict__ PAN,
                             float* __restrict__ partH, float* __restrict__ partP) {
    int g = blockIdx.x * 256 + threadIdx.x;          // (b*CC + c)*LL + l
    if (g >= BB * CC * LL) return;
    int l = g % LL;
    int y = div80(l), x = l - y * 80;
    const float* hc = HSI + (size_t)(g - l);
    const float* pc = PAN + (size_t)(g - l);
    float sh = 0.f, sp = 0.f;
    #pragma unroll
    for (int i = 0; i < 3; ++i) {
        int yy = y + i - 1;
        if ((unsigned)yy >= 80u) continue;
        #pragma unroll
        for (int j = 0; j < 3; ++j) {
            int xx = x + j - 1;
            if ((unsigned)xx >= 80u) continue;
            float hv = hc[yy * 80 + xx]; sh = fmaf(hv, hv, sh);
            float pv = pc[yy * 80 + xx]; sp = fmaf(pv, pv, sp);
        }
    }
    partH[g] = sh;
    partP[g] = sp;
}

// ---------------- prep2: reduce over channels -> inverse norms ----------------
__global__ void prep2_kernel(const float* __restrict__ partH, const float* __restrict__ partP,
                             float* __restrict__ invH, float* __restrict__ invP) {
    int g = blockIdx.x * 256 + threadIdx.x;          // b*LL + l
    if (g >= BB * LL) return;
    int b = g / LL, l = g - b * LL;
    float sh = 0.f, sp = 0.f;
    #pragma unroll
    for (int c = 0; c < CC; ++c) {
        sh += partH[((size_t)(b * CC + c)) * LL + l];
        sp += partP[((size_t)(b * CC + c)) * LL + l];
    }
    invH[g] = 1.f / fmaxf(sqrtf(sh), 1e-12f);
    invP[g] = 1.f / fmaxf(sqrtf(sp), 1e-12f);
}

// ---------------- pack: normalized unfold columns -> bf16 (hi only), swizzled rows ----------------
__global__ void pack_kernel(const float* __restrict__ HSI, const float* __restrict__ PAN,
                            const float* __restrict__ invH, const float* __restrict__ invP,
                            char* __restrict__ Apack, char* __restrict__ Bpack) {
    int t = blockIdx.x * 256 + threadIdx.x;
    if (t >= BB * 2 * LL * 36) return;
    int g = t % 36;
    int rest = t / 36;
    int l = rest % LL; rest /= LL;
    int mat = rest & 1;      // 0 = PAN (A operand), 1 = HSI (B operand)
    int b = rest >> 1;
    const float* img = (mat ? HSI : PAN) + (size_t)b * CC * LL;
    float inv = (mat ? invH : invP)[b * LL + l];
    int y = div80(l), x = l - y * 80;
    int k0 = g * 8;
    int c = k0 / 9, tap = k0 - c * 9;
    unsigned short hs[8];
    #pragma unroll
    for (int j = 0; j < 8; ++j) {
        int t3 = tap / 3;
        int dy = t3 - 1, dx = tap - t3 * 3 - 1;
        int yy = y + dy, xx = x + dx;
        float val = ((unsigned)yy < 80u && (unsigned)xx < 80u)
                        ? img[(size_t)c * LL + yy * 80 + xx] * inv : 0.f;
        hs[j] = f2bf(val);
        if (++tap == 9) { tap = 0; ++c; }
    }
    char* pk = mat ? Bpack : Apack;
    int slot = (g % 12) ^ (l & 15);
    int q = g / 12;
    size_t off = ((size_t)(b * 3 + q) * LL + l) * 256 + slot * 16;
    uint4 hv;
    hv.x = hs[0] | ((unsigned)hs[1] << 16); hv.y = hs[2] | ((unsigned)hs[3] << 16);
    hv.z = hs[4] | ((unsigned)hs[5] << 16); hv.w = hs[6] | ((unsigned)hs[7] << 16);
    *(uint4*)(pk + off) = hv;
}

// ---------------- simq: MFMA similarity (hi-only, K=288), per-(16l-subtile, m) max ----------------
__global__ __launch_bounds__(256) void simq_kernel(const char* __restrict__ Apack,
                                                   const char* __restrict__ Bpack,
                                                   float* __restrict__ tileMax16) {
    __shared__ __align__(16) char Alds[32768];
    __shared__ __align__(16) char Blds[32768];
    // bijective XCD swizzle for nwg=500: q=62, r=4
    const int orig = blockIdx.x;
    const int xcd = orig & 7, idx = orig >> 3;
    const int wg = (xcd < 4 ? xcd * 63 : 252 + (xcd - 4) * 62) + idx;
    const int b = wg / 250;
    int rest = wg - b * 250;
    const int sp = rest / 50;
    const int mt = rest - sp * 50;

    const int tid = threadIdx.x;
    const int lane = tid & 63, w = tid >> 6;
    const int wl = w >> 1, wm = w & 1;
    const int r15 = lane & 15, h = lane >> 4;
    const char* Ab = Apack + (size_t)b * 3 * LL * 256;
    const char* Bb = Bpack + (size_t)b * 3 * LL * 256;
    const int m0 = mt * 128;
    const f32x4 fzero = {0.f, 0.f, 0.f, 0.f};

    #pragma unroll 1
    for (int lt = 0; lt < 10; ++lt) {
        const int l0 = (sp * 10 + lt) * 128;
        f32x4 acc[4][4];
        #pragma unroll
        for (int i = 0; i < 4; ++i)
            #pragma unroll
            for (int j = 0; j < 4; ++j) acc[i][j] = fzero;

        #pragma unroll 1
        for (int c = 0; c < 3; ++c) {
            __syncthreads();
            const char* gA = Ab + ((size_t)c * LL + l0) * 256 + w * 8192 + lane * 16;
            const char* gB = Bb + ((size_t)c * LL + m0) * 256 + w * 8192 + lane * 16;
            char* lA = Alds + w * 8192;
            char* lB = Blds + w * 8192;
            #pragma unroll
            for (int i = 0; i < 8; ++i) {
                gload_lds16((void*)(gA + i * 1024), lA + i * 1024);
                gload_lds16((void*)(gB + i * 1024), lB + i * 1024);
            }
            __syncthreads();
            #pragma unroll
            for (int ks = 0; ks < 3; ++ks) {
                const int gp = ((ks * 4 + h) ^ r15) * 16;
                bf16x8 af[4], bfr[4];
                #pragma unroll
                for (int f = 0; f < 4; ++f) {
                    af[f]  = *(const bf16x8*)(Alds + (wl * 64 + f * 16 + r15) * 256 + gp);
                    bfr[f] = *(const bf16x8*)(Blds + (wm * 64 + f * 16 + r15) * 256 + gp);
                }
                #pragma unroll
                for (int fl = 0; fl < 4; ++fl)
                    #pragma unroll
                    for (int fm = 0; fm < 4; ++fm)
                        acc[fl][fm] = __builtin_amdgcn_mfma_f32_16x16x32_bf16(
                            af[fl], bfr[fm], acc[fl][fm], 0, 0, 0);
            }
        }
        // fold: per m-col max over each 16-l subtile (fl), m-major output
        const int Tbase = (sp * 10 + lt) * 8 + wl * 4;
        #pragma unroll
        for (int fl = 0; fl < 4; ++fl) {
            #pragma unroll
            for (int fm = 0; fm < 4; ++fm) {
                f32x4 a = acc[fl][fm];
                float v = fmaxf(fmaxf(a[0], a[1]), fmaxf(a[2], a[3]));
                v = fmaxf(v, __shfl_xor(v, 16, 64));
                v = fmaxf(v, __shfl_xor(v, 32, 64));
                if (h == 0) {
                    const int m = m0 + wm * 64 + fm * 16 + r15;
                    tileMax16[((size_t)b * LL + m) * NT16 + Tbase + fl] = v;
                }
            }
        }
    }
}

// ---------------- scanfix: wave-per-(b,m) threshold scan + exact fp32 rescore ----------------
__global__ __launch_bounds__(256) void scanfix_kernel(const float* __restrict__ HSI,
                                                      const float* __restrict__ PAN,
                                                      const float* __restrict__ invH,
                                                      const float* __restrict__ invP,
                                                      const float* __restrict__ tileMax16,
                                                      float* __restrict__ Sv, int* __restrict__ Sa) {
    const int gw = blockIdx.x * 4 + (threadIdx.x >> 6);   // b*LL + m
    const int lane = threadIdx.x & 63;
    const int b = gw / LL, m = gw - b * LL;
    const float* tm = tileMax16 + (size_t)gw * NT16;

    float tv[7];
    #pragma unroll
    for (int i = 0; i < 7; ++i) {
        int T = i * 64 + lane;
        tv[i] = (T < NT16) ? tm[T] : -3.0e38f;
    }
    float v1 = tv[0];
    #pragma unroll
    for (int i = 1; i < 7; ++i) v1 = fmaxf(v1, tv[i]);
    #pragma unroll
    for (int d = 1; d < 64; d <<= 1) v1 = fmaxf(v1, __shfl_xor(v1, d, 64));
    const float th = v1 - DELTA;

    const int ym = div80(m), xm = m - ym * 80;
    const float ihm = invH[gw];
    const size_t hb = (size_t)b * CC * LL;
    const int lql = lane >> 2, kq = lane & 3;

    // hoisted bounds/offsets for m's patch taps
    bool hok[9]; int hoff[9];
    #pragma unroll
    for (int i3 = 0; i3 < 3; ++i3)
        #pragma unroll
        for (int j3 = 0; j3 < 3; ++j3) {
            int yy = ym + i3 - 1, xx = xm + j3 - 1;
            hok[i3 * 3 + j3] = ((unsigned)yy < 80u && (unsigned)xx < 80u);
            hoff[i3 * 3 + j3] = yy * 80 + xx;
        }

    float bv = -3.0e38f; int bl = 0x7fffffff;

    #pragma unroll 1
    for (int i = 0; i < 7; ++i) {
        unsigned long long mask = __ballot(tv[i] >= th);
        while (mask) {
            const int t = __ffsll((long long)mask) - 1;
            mask &= mask - 1;
            const int T = i * 64 + t;
            const int l = T * 16 + lql;
            const int y = div80(l), x = l - y * 80;
            bool pok[9]; int poff[9];
            #pragma unroll
            for (int i3 = 0; i3 < 3; ++i3)
                #pragma unroll
                for (int j3 = 0; j3 < 3; ++j3) {
                    int yy = y + i3 - 1, xx = x + j3 - 1;
                    pok[i3 * 3 + j3] = ((unsigned)yy < 80u && (unsigned)xx < 80u);
                    poff[i3 * 3 + j3] = yy * 80 + xx;
                }
            float part = 0.f;
            #pragma unroll 1
            for (int cc = 0; cc < 8; ++cc) {
                const float* Pimg = PAN + hb + (size_t)(kq * 8 + cc) * LL;
                const float* Himg = HSI + hb + (size_t)(kq * 8 + cc) * LL;
                #pragma unroll
                for (int t9 = 0; t9 < 9; ++t9) {
                    float av = pok[t9] ? Pimg[poff[t9]] : 0.f;
                    float hv = hok[t9] ? Himg[hoff[t9]] : 0.f;
                    part = fmaf(av, hv, part);
                }
            }
            // replicate round-3 order: ((q0+q1)+q2)+q3, then *invP*invH
            const int base = lane & ~3;
            float q0 = __shfl(part, base,     64);
            float q1 = __shfl(part, base + 1, 64);
            float q2 = __shfl(part, base + 2, 64);
            float q3 = __shfl(part, base + 3, 64);
            float val = ((q0 + q1) + q2) + q3;
            val = val * invP[b * LL + l] * ihm;
            if (val > bv || (val == bv && l < bl)) { bv = val; bl = l; }
        }
    }
    // wave reduce with first-max tie rule
    #pragma unroll
    for (int d = 1; d < 64; d <<= 1) {
        float ov = __shfl_xor(bv, d, 64);
        int   ol = __shfl_xor(bl, d, 64);
        if (ov > bv || (ov == bv && ol < bl)) { bv = ov; bl = ol; }
    }
    if (lane == 0) { Sv[gw] = bv; Sa[gw] = bl; }
}

// ---------------- T_lv3 = fold3x3(gathered PAN patches) / 9 ----------------
__global__ void tfold_kernel(const float* __restrict__ PAN, const int* __restrict__ Sa,
                             float* __restrict__ T) {
    int g = blockIdx.x * blockDim.x + threadIdx.x;
    if (g >= BB * CC * LL) return;
    int bc = g / LL, l = g - bc * LL;
    int b = bc >> 5;
    int y = div80(l), x = l - y * 80;
    const float* img = PAN + (size_t)bc * LL;
    const int* Sab = Sa + b * LL;
    float acc = 0.f;
    #pragma unroll
    for (int i = 0; i < 3; ++i) {
        int yp = y + 1 - i;
        if ((unsigned)yp >= 80u) continue;
        #pragma unroll
        for (int j = 0; j < 3; ++j) {
            int xp = x + 1 - j;
            if ((unsigned)xp >= 80u) continue;
            int a = Sab[yp * 80 + xp];
            int ya = div80(a), xa = a - ya * 80;
            int py = ya + i - 1, px = xa + j - 1;
            if ((unsigned)py < 80u && (unsigned)px < 80u) acc += img[py * 80 + px];
        }
    }
    T[g] = acc * (1.f / 9.f);
}

// ---------------- conv1: h = relu(conv3x3(concat(T,HSI), w1) + b1) ----------------
__global__ __launch_bounds__(256) void conv1_kernel(const float* __restrict__ T,
                                                    const float* __restrict__ HSI,
                                                    const float* __restrict__ w1,
                                                    const float* __restrict__ b1,
                                                    float* __restrict__ h) {
    __shared__ __align__(16) float wl[64][9][COG];
    const int tid = threadIdx.x;
    const int co0 = blockIdx.y * COG;
    for (int idx = tid; idx < 64 * 9 * COG; idx += 256) {
        int cog = idx & (COG - 1);
        int rest = idx >> 3;
        int cin = rest / 9, tap = rest - cin * 9;
        wl[cin][tap][cog] = w1[(co0 + cog) * (64 * 9) + cin * 9 + tap];
    }
    __syncthreads();
    const int g = blockIdx.x * 256 + tid;
    const int b = g / LL, l = g - b * LL;
    const int y = div80(l), x = l - y * 80;
    float acc[COG];
    #pragma unroll
    for (int i = 0; i < COG; ++i) acc[i] = 0.f;
    for (int cin = 0; cin < 64; ++cin) {
        const float* img = (cin < CC) ? (T + (size_t)(b * CC + cin) * LL)
                                      : (HSI + (size_t)(b * CC + (cin - CC)) * LL);
        float tap[9];
        #pragma unroll
        for (int i = 0; i < 3; ++i)
            #pragma unroll
            for (int j = 0; j < 3; ++j) {
                int yy = y + i - 1, xx = x + j - 1;
                tap[i * 3 + j] = ((unsigned)yy < 80u && (unsigned)xx < 80u) ? img[yy * 80 + xx] : 0.f;
            }
        #pragma unroll
        for (int t9 = 0; t9 < 9; ++t9) {
            const float4 wa = *reinterpret_cast<const float4*>(&wl[cin][t9][0]);
            const float4 wb = *reinterpret_cast<const float4*>(&wl[cin][t9][4]);
            acc[0] = fmaf(tap[t9], wa.x, acc[0]);
            acc[1] = fmaf(tap[t9], wa.y, acc[1]);
            acc[2] = fmaf(tap[t9], wa.z, acc[2]);
            acc[3] = fmaf(tap[t9], wa.w, acc[3]);
            acc[4] = fmaf(tap[t9], wb.x, acc[4]);
            acc[5] = fmaf(tap[t9], wb.y, acc[5]);
            acc[6] = fmaf(tap[t9], wb.z, acc[6]);
            acc[7] = fmaf(tap[t9], wb.w, acc[7]);
        }
    }
    #pragma unroll
    for (int cog = 0; cog < COG; ++cog) {
        float v = acc[cog] + b1[co0 + cog];
        h[(size_t)(b * CC + co0 + cog) * LL + l] = fmaxf(v, 0.f);
    }
}

// ---------------- conv2: out = (conv3x3(h, w2) + b2) * S + HSI ----------------
__global__ __launch_bounds__(256) void conv2_kernel(const float* __restrict__ hbuf,
                                                    const float* __restrict__ HSI,
                                                    const float* __restrict__ Sv,
                                                    const float* __restrict__ w2,
                                                    const float* __restrict__ b2,
                                                    float* __restrict__ out) {
    __shared__ __align__(16) float wl[CC][9][COG];
    const int tid = threadIdx.x;
    const int co0 = blockIdx.y * COG;
    for (int idx = tid; idx < CC * 9 * COG; idx += 256) {
        int cog = idx & (COG - 1);
        int rest = idx >> 3;
        int cin = rest / 9, tap = rest - cin * 9;
        wl[cin][tap][cog] = w2[(co0 + cog) * (CC * 9) + cin * 9 + tap];
    }
    __syncthreads();
    const int g = blockIdx.x * 256 + tid;
    const int b = g / LL, l = g - b * LL;
    const int y = div80(l), x = l - y * 80;
    float acc[COG];
    #pragma unroll
    for (int i = 0; i < COG; ++i) acc[i] = 0.f;
    for (int cin = 0; cin < CC; ++cin) {
        const float* img = hbuf + (size_t)(b * CC + cin) * LL;
        float tap[9];
        #pragma unroll
        for (int i = 0; i < 3; ++i)
            #pragma unroll
            for (int j = 0; j < 3; ++j) {
                int yy = y + i - 1, xx = x + j - 1;
                tap[i * 3 + j] = ((unsigned)yy < 80u && (unsigned)xx < 80u) ? img[yy * 80 + xx] : 0.f;
            }
        #pragma unroll
        for (int t9 = 0; t9 < 9; ++t9) {
            const float4 wa = *reinterpret_cast<const float4*>(&wl[cin][t9][0]);
            const float4 wb = *reinterpret_cast<const float4*>(&wl[cin][t9][4]);
            acc[0] = fmaf(tap[t9], wa.x, acc[0]);
            acc[1] = fmaf(tap[t9], wa.y, acc[1]);
            acc[2] = fmaf(tap[t9], wa.z, acc[2]);
            acc[3] = fmaf(tap[t9], wa.w, acc[3]);
            acc[4] = fmaf(tap[t9], wb.x, acc[4]);
            acc[5] = fmaf(tap[t9], wb.y, acc[5]);
            acc[6] = fmaf(tap[t9], wb.z, acc[6]);
            acc[7] = fmaf(tap[t9], wb.w, acc[7]);
        }
    }
    const float s = Sv[b * LL + l];
    #pragma unroll
    for (int cog = 0; cog < COG; ++cog) {
        int c = co0 + cog;
        out[(size_t)(b * CC + c) * LL + l] = fmaf(acc[cog] + b2[c], s, HSI[(size_t)(b * CC + c) * LL + l]);
    }
}

extern "C" void kernel_launch(void* const* d_in, const int* in_sizes, int n_in,
                              void* d_out, int out_size, void* d_ws, size_t ws_size,
                              hipStream_t stream) {
    const float* HSI = (const float*)d_in[0];
    const float* PAN = (const float*)d_in[1];
    const float* w1  = (const float*)d_in[2];
    const float* b1  = (const float*)d_in[3];
    const float* w2  = (const float*)d_in[4];
    const float* b2  = (const float*)d_in[5];
    float* out = (float*)d_out;

    char* ws = (char*)d_ws;
    size_t off = 0;
    auto alloc = [&](size_t bytes) -> void* {
        void* p = ws + off;
        off += (bytes + 255) & ~(size_t)255;
        return p;
    };
    float* partH = (float*)alloc((size_t)BB * CC * LL * 4);
    float* partP = (float*)alloc((size_t)BB * CC * LL * 4);
    float* invH  = (float*)alloc((size_t)BB * LL * 4);
    float* invP  = (float*)alloc((size_t)BB * LL * 4);
    char*  Apack = (char*) alloc((size_t)BB * 3 * LL * 256);
    char*  Bpack = (char*) alloc((size_t)BB * 3 * LL * 256);
    float* tileMax16 = (float*)alloc((size_t)BB * LL * NT16 * 4);  // 20.5 MB
    float* Sv    = (float*)alloc((size_t)BB * LL * 4);
    int*   Sa    = (int*)  alloc((size_t)BB * LL * 4);
    float* T     = (float*)alloc((size_t)BB * CC * LL * 4);
    float* hbuf  = (float*)alloc((size_t)BB * CC * LL * 4);

    prep1_kernel<<<dim3((BB * CC * LL + 255) / 256), 256, 0, stream>>>(HSI, PAN, partH, partP);
    prep2_kernel<<<dim3((BB * LL + 255) / 256), 256, 0, stream>>>(partH, partP, invH, invP);
    pack_kernel<<<dim3((BB * 2 * LL * 36 + 255) / 256), 256, 0, stream>>>(HSI, PAN, invH, invP, Apack, Bpack);
    simq_kernel<<<dim3(500), 256, 0, stream>>>(Apack, Bpack, tileMax16);
    scanfix_kernel<<<dim3(BB * LL / 4), 256, 0, stream>>>(HSI, PAN, invH, invP, tileMax16, Sv, Sa);
    tfold_kernel<<<dim3((BB * CC * LL + 255) / 256), 256, 0, stream>>>(PAN, Sa, T);
    conv1_kernel<<<dim3(BB * LL / 256, CC / COG), 256, 0, stream>>>(T, HSI, w1, b1, hbuf);
    conv2_kernel<<<dim3(BB * LL / 256, CC / COG), 256, 0, stream>>>(hbuf, HSI, Sv, w2, b2, out);
}

// Round 5
// 291.928 us; speedup vs baseline: 5.1257x; 1.1374x over previous
//
#include <hip/hip_runtime.h>
#include <hip/hip_bf16.h>
#include <hip/hip_fp16.h>
#include <stdint.h>

#define HH 80
#define WW 80
#define LL 6400
#define CC 32
#define BB 2
#define COG 8
#define DELTA 0.011f
#define NT8 800

typedef __bf16 bf16x8 __attribute__((ext_vector_type(8)));
typedef float  f32x4  __attribute__((ext_vector_type(4)));

__device__ __forceinline__ int div80(int v) {
    return (int)(((unsigned)v * 52429u) >> 22);   // exact for 0 <= v < 52428
}

__device__ __forceinline__ unsigned short f2bf(float f) {
    unsigned int u = __float_as_uint(f);
    return (unsigned short)((u + 0x7fffu + ((u >> 16) & 1u)) >> 16);   // RNE
}

__device__ __forceinline__ void gload_lds16(void* g, void* l) {
    __builtin_amdgcn_global_load_lds(
        (__attribute__((address_space(1))) void*)g,
        (__attribute__((address_space(3))) void*)l, 16, 0, 0);
}

// ---------------- prep1: per-(b,c,l) 3x3 squared-sums ----------------
__global__ void prep1_kernel(const float* __restrict__ HSI, const float* __restrict__ PAN,
                             float* __restrict__ partH, float* __restrict__ partP) {
    int g = blockIdx.x * 256 + threadIdx.x;          // (b*CC + c)*LL + l
    if (g >= BB * CC * LL) return;
    int l = g % LL;
    int y = div80(l), x = l - y * 80;
    const float* hc = HSI + (size_t)(g - l);
    const float* pc = PAN + (size_t)(g - l);
    float sh = 0.f, sp = 0.f;
    #pragma unroll
    for (int i = 0; i < 3; ++i) {
        int yy = y + i - 1;
        if ((unsigned)yy >= 80u) continue;
        #pragma unroll
        for (int j = 0; j < 3; ++j) {
            int xx = x + j - 1;
            if ((unsigned)xx >= 80u) continue;
            float hv = hc[yy * 80 + xx]; sh = fmaf(hv, hv, sh);
            float pv = pc[yy * 80 + xx]; sp = fmaf(pv, pv, sp);
        }
    }
    partH[g] = sh;
    partP[g] = sp;
}

// ---------------- prep2: reduce over channels -> inverse norms ----------------
__global__ void prep2_kernel(const float* __restrict__ partH, const float* __restrict__ partP,
                             float* __restrict__ invH, float* __restrict__ invP) {
    int g = blockIdx.x * 256 + threadIdx.x;          // b*LL + l
    if (g >= BB * LL) return;
    int b = g / LL, l = g - b * LL;
    float sh = 0.f, sp = 0.f;
    #pragma unroll
    for (int c = 0; c < CC; ++c) {
        sh += partH[((size_t)(b * CC + c)) * LL + l];
        sp += partP[((size_t)(b * CC + c)) * LL + l];
    }
    invH[g] = 1.f / fmaxf(sqrtf(sh), 1e-12f);
    invP[g] = 1.f / fmaxf(sqrtf(sp), 1e-12f);
}

// ---------------- pack: normalized unfold columns -> bf16 (hi only), swizzled rows ----------------
__global__ void pack_kernel(const float* __restrict__ HSI, const float* __restrict__ PAN,
                            const float* __restrict__ invH, const float* __restrict__ invP,
                            char* __restrict__ Apack, char* __restrict__ Bpack) {
    int t = blockIdx.x * 256 + threadIdx.x;
    if (t >= BB * 2 * LL * 36) return;
    int g = t % 36;
    int rest = t / 36;
    int l = rest % LL; rest /= LL;
    int mat = rest & 1;      // 0 = PAN (A operand), 1 = HSI (B operand)
    int b = rest >> 1;
    const float* img = (mat ? HSI : PAN) + (size_t)b * CC * LL;
    float inv = (mat ? invH : invP)[b * LL + l];
    int y = div80(l), x = l - y * 80;
    int k0 = g * 8;
    int c = k0 / 9, tap = k0 - c * 9;
    unsigned short hs[8];
    #pragma unroll
    for (int j = 0; j < 8; ++j) {
        int t3 = tap / 3;
        int dy = t3 - 1, dx = tap - t3 * 3 - 1;
        int yy = y + dy, xx = x + dx;
        float val = ((unsigned)yy < 80u && (unsigned)xx < 80u)
                        ? img[(size_t)c * LL + yy * 80 + xx] * inv : 0.f;
        hs[j] = f2bf(val);
        if (++tap == 9) { tap = 0; ++c; }
    }
    char* pk = mat ? Bpack : Apack;
    int slot = (g % 12) ^ (l & 15);
    int q = g / 12;
    size_t off = ((size_t)(b * 3 + q) * LL + l) * 256 + slot * 16;
    uint4 hv;
    hv.x = hs[0] | ((unsigned)hs[1] << 16); hv.y = hs[2] | ((unsigned)hs[3] << 16);
    hv.z = hs[4] | ((unsigned)hs[5] << 16); hv.w = hs[6] | ((unsigned)hs[7] << 16);
    *(uint4*)(pk + off) = hv;
}

// ---------------- simq: MFMA similarity (hi-only, K=288), per-(8l-subtile, m) max ----------------
__global__ __launch_bounds__(256) void simq_kernel(const char* __restrict__ Apack,
                                                   const char* __restrict__ Bpack,
                                                   __half* __restrict__ tileMax8) {
    __shared__ __align__(16) char Alds[32768];
    __shared__ __align__(16) char Blds[32768];
    // bijective XCD swizzle for nwg=500: q=62, r=4
    const int orig = blockIdx.x;
    const int xcd = orig & 7, idx = orig >> 3;
    const int wg = (xcd < 4 ? xcd * 63 : 252 + (xcd - 4) * 62) + idx;
    const int b = wg / 250;
    int rest = wg - b * 250;
    const int sp = rest / 50;
    const int mt = rest - sp * 50;

    const int tid = threadIdx.x;
    const int lane = tid & 63, w = tid >> 6;
    const int wl = w >> 1, wm = w & 1;
    const int r15 = lane & 15, h = lane >> 4;
    const char* Ab = Apack + (size_t)b * 3 * LL * 256;
    const char* Bb = Bpack + (size_t)b * 3 * LL * 256;
    const int m0 = mt * 128;
    const f32x4 fzero = {0.f, 0.f, 0.f, 0.f};

    #pragma unroll 1
    for (int lt = 0; lt < 10; ++lt) {
        const int l0 = (sp * 10 + lt) * 128;
        f32x4 acc[4][4];
        #pragma unroll
        for (int i = 0; i < 4; ++i)
            #pragma unroll
            for (int j = 0; j < 4; ++j) acc[i][j] = fzero;

        #pragma unroll 1
        for (int c = 0; c < 3; ++c) {
            __syncthreads();
            const char* gA = Ab + ((size_t)c * LL + l0) * 256 + w * 8192 + lane * 16;
            const char* gB = Bb + ((size_t)c * LL + m0) * 256 + w * 8192 + lane * 16;
            char* lA = Alds + w * 8192;
            char* lB = Blds + w * 8192;
            #pragma unroll
            for (int i = 0; i < 8; ++i) {
                gload_lds16((void*)(gA + i * 1024), lA + i * 1024);
                gload_lds16((void*)(gB + i * 1024), lB + i * 1024);
            }
            __syncthreads();
            #pragma unroll
            for (int ks = 0; ks < 3; ++ks) {
                const int gp = ((ks * 4 + h) ^ r15) * 16;
                bf16x8 af[4], bfr[4];
                #pragma unroll
                for (int f = 0; f < 4; ++f) {
                    af[f]  = *(const bf16x8*)(Alds + (wl * 64 + f * 16 + r15) * 256 + gp);
                    bfr[f] = *(const bf16x8*)(Blds + (wm * 64 + f * 16 + r15) * 256 + gp);
                }
                #pragma unroll
                for (int fl = 0; fl < 4; ++fl)
                    #pragma unroll
                    for (int fm = 0; fm < 4; ++fm)
                        acc[fl][fm] = __builtin_amdgcn_mfma_f32_16x16x32_bf16(
                            af[fl], bfr[fm], acc[fl][fm], 0, 0, 0);
            }
        }
        // fold: per m-col max over each 8-l subtile; C layout row = h*4 + reg
        const int Tbase = (sp * 10 + lt) * 16 + wl * 8;
        #pragma unroll
        for (int fl = 0; fl < 4; ++fl) {
            #pragma unroll
            for (int fm = 0; fm < 4; ++fm) {
                f32x4 a = acc[fl][fm];
                float v = fmaxf(fmaxf(a[0], a[1]), fmaxf(a[2], a[3]));   // 4-row max (rows h*4..h*4+3)
                v = fmaxf(v, __shfl_xor(v, 16, 64));                      // pair h with h^1 -> 8-row max
                if ((h & 1) == 0) {
                    const int m = m0 + wm * 64 + fm * 16 + r15;
                    tileMax8[((size_t)b * LL + m) * NT8 + Tbase + fl * 2 + (h >> 1)] = __float2half(v);
                }
            }
        }
    }
}

// ---------------- scanfix: wave-per-(b,m) threshold scan + exact fp32 rescore ----------------
// lane = (lql = l within 8-subtile) x (kq = k-octant: 4 channels x 9 taps = 36 k)
__global__ __launch_bounds__(256) void scanfix_kernel(const float* __restrict__ HSI,
                                                      const float* __restrict__ PAN,
                                                      const float* __restrict__ invH,
                                                      const float* __restrict__ invP,
                                                      const __half* __restrict__ tileMax8,
                                                      float* __restrict__ Sv, int* __restrict__ Sa) {
    const int gw = blockIdx.x * 4 + (threadIdx.x >> 6);   // b*LL + m
    const int lane = threadIdx.x & 63;
    const int b = gw / LL, m = gw - b * LL;
    const __half* tm = tileMax8 + (size_t)gw * NT8;

    float tv[13];
    #pragma unroll
    for (int i = 0; i < 13; ++i) {
        int T = i * 64 + lane;
        tv[i] = (T < NT8) ? __half2float(tm[T]) : -3.0e38f;
    }
    float v1 = tv[0];
    #pragma unroll
    for (int i = 1; i < 13; ++i) v1 = fmaxf(v1, tv[i]);
    #pragma unroll
    for (int d = 1; d < 64; d <<= 1) v1 = fmaxf(v1, __shfl_xor(v1, d, 64));
    const float th = v1 - DELTA;

    const int ym = div80(m), xm = m - ym * 80;
    const float ihm = invH[gw];
    const size_t hb = (size_t)b * CC * LL;
    const int lql = lane >> 3, kq = lane & 7;

    // hoisted HSI column (m fixed per wave): 4 channels x 9 taps per lane
    float hreg[36];
    {
        bool hok[9]; int hoff[9];
        #pragma unroll
        for (int i3 = 0; i3 < 3; ++i3)
            #pragma unroll
            for (int j3 = 0; j3 < 3; ++j3) {
                int yy = ym + i3 - 1, xx = xm + j3 - 1;
                hok[i3 * 3 + j3] = ((unsigned)yy < 80u && (unsigned)xx < 80u);
                hoff[i3 * 3 + j3] = yy * 80 + xx;
            }
        #pragma unroll
        for (int cc2 = 0; cc2 < 4; ++cc2) {
            const float* Himg = HSI + hb + (size_t)(kq * 4 + cc2) * LL;
            #pragma unroll
            for (int t9 = 0; t9 < 9; ++t9)
                hreg[cc2 * 9 + t9] = hok[t9] ? Himg[hoff[t9]] : 0.f;
        }
    }

    float bv = -3.0e38f; int bl = 0x7fffffff;

    #pragma unroll 1
    for (int i = 0; i < 13; ++i) {
        unsigned long long mask = __ballot(tv[i] >= th);
        while (mask) {
            const int t = __ffsll((long long)mask) - 1;
            mask &= mask - 1;
            const int T = i * 64 + t;
            const int l8 = T * 8;                 // 8-aligned runs never cross a row (80 % 8 == 0)
            const int y = div80(l8), x0 = l8 - y * 80;
            const int x = x0 + lql;
            const int l = l8 + lql;
            const bool vy0 = (y >= 1), vy2 = (y <= 78);
            const bool vx0 = (x >= 1), vx2 = (x <= 78);
            bool pok[9]; int poff[9];
            #pragma unroll
            for (int dy = 0; dy < 3; ++dy) {
                const bool vy = (dy == 1) ? true : (dy == 0 ? vy0 : vy2);
                #pragma unroll
                for (int dx = 0; dx < 3; ++dx) {
                    const bool vx = (dx == 1) ? true : (dx == 0 ? vx0 : vx2);
                    pok[dy * 3 + dx] = vy && vx;
                    poff[dy * 3 + dx] = (y + dy - 1) * 80 + x + dx - 1;
                }
            }
            float part = 0.f;
            #pragma unroll
            for (int cc2 = 0; cc2 < 4; ++cc2) {
                const float* Pimg = PAN + hb + (size_t)(kq * 4 + cc2) * LL;
                #pragma unroll
                for (int t9 = 0; t9 < 9; ++t9)
                    part = fmaf(pok[t9] ? Pimg[poff[t9]] : 0.f, hreg[cc2 * 9 + t9], part);
            }
            // reduce over kq (lanes lql*8 .. lql*8+7)
            part += __shfl_xor(part, 1, 64);
            part += __shfl_xor(part, 2, 64);
            part += __shfl_xor(part, 4, 64);
            const float val = part * invP[b * LL + l] * ihm;
            if (val > bv || (val == bv && l < bl)) { bv = val; bl = l; }
        }
    }
    // wave reduce with first-max tie rule (duplicates across kq carry identical (val,l))
    #pragma unroll
    for (int d = 1; d < 64; d <<= 1) {
        float ov = __shfl_xor(bv, d, 64);
        int   ol = __shfl_xor(bl, d, 64);
        if (ov > bv || (ov == bv && ol < bl)) { bv = ov; bl = ol; }
    }
    if (lane == 0) { Sv[gw] = bv; Sa[gw] = bl; }
}

// ---------------- T_lv3 = fold3x3(gathered PAN patches) / 9 ----------------
__global__ void tfold_kernel(const float* __restrict__ PAN, const int* __restrict__ Sa,
                             float* __restrict__ T) {
    int g = blockIdx.x * blockDim.x + threadIdx.x;
    if (g >= BB * CC * LL) return;
    int bc = g / LL, l = g - bc * LL;
    int b = bc >> 5;
    int y = div80(l), x = l - y * 80;
    const float* img = PAN + (size_t)bc * LL;
    const int* Sab = Sa + b * LL;
    float acc = 0.f;
    #pragma unroll
    for (int i = 0; i < 3; ++i) {
        int yp = y + 1 - i;
        if ((unsigned)yp >= 80u) continue;
        #pragma unroll
        for (int j = 0; j < 3; ++j) {
            int xp = x + 1 - j;
            if ((unsigned)xp >= 80u) continue;
            int a = Sab[yp * 80 + xp];
            int ya = div80(a), xa = a - ya * 80;
            int py = ya + i - 1, px = xa + j - 1;
            if ((unsigned)py < 80u && (unsigned)px < 80u) acc += img[py * 80 + px];
        }
    }
    T[g] = acc * (1.f / 9.f);
}

// ---------------- conv1: h = relu(conv3x3(concat(T,HSI), w1) + b1) ----------------
__global__ __launch_bounds__(256) void conv1_kernel(const float* __restrict__ T,
                                                    const float* __restrict__ HSI,
                                                    const float* __restrict__ w1,
                                                    const float* __restrict__ b1,
                                                    float* __restrict__ h) {
    __shared__ __align__(16) float wl[64][9][COG];
    const int tid = threadIdx.x;
    const int co0 = blockIdx.y * COG;
    for (int idx = tid; idx < 64 * 9 * COG; idx += 256) {
        int cog = idx & (COG - 1);
        int rest = idx >> 3;
        int cin = rest / 9, tap = rest - cin * 9;
        wl[cin][tap][cog] = w1[(co0 + cog) * (64 * 9) + cin * 9 + tap];
    }
    __syncthreads();
    const int g = blockIdx.x * 256 + tid;
    const int b = g / LL, l = g - b * LL;
    const int y = div80(l), x = l - y * 80;
    float acc[COG];
    #pragma unroll
    for (int i = 0; i < COG; ++i) acc[i] = 0.f;
    for (int cin = 0; cin < 64; ++cin) {
        const float* img = (cin < CC) ? (T + (size_t)(b * CC + cin) * LL)
                                      : (HSI + (size_t)(b * CC + (cin - CC)) * LL);
        float tap[9];
        #pragma unroll
        for (int i = 0; i < 3; ++i)
            #pragma unroll
            for (int j = 0; j < 3; ++j) {
                int yy = y + i - 1, xx = x + j - 1;
                tap[i * 3 + j] = ((unsigned)yy < 80u && (unsigned)xx < 80u) ? img[yy * 80 + xx] : 0.f;
            }
        #pragma unroll
        for (int t9 = 0; t9 < 9; ++t9) {
            const float4 wa = *reinterpret_cast<const float4*>(&wl[cin][t9][0]);
            const float4 wb = *reinterpret_cast<const float4*>(&wl[cin][t9][4]);
            acc[0] = fmaf(tap[t9], wa.x, acc[0]);
            acc[1] = fmaf(tap[t9], wa.y, acc[1]);
            acc[2] = fmaf(tap[t9], wa.z, acc[2]);
            acc[3] = fmaf(tap[t9], wa.w, acc[3]);
            acc[4] = fmaf(tap[t9], wb.x, acc[4]);
            acc[5] = fmaf(tap[t9], wb.y, acc[5]);
            acc[6] = fmaf(tap[t9], wb.z, acc[6]);
            acc[7] = fmaf(tap[t9], wb.w, acc[7]);
        }
    }
    #pragma unroll
    for (int cog = 0; cog < COG; ++cog) {
        float v = acc[cog] + b1[co0 + cog];
        h[(size_t)(b * CC + co0 + cog) * LL + l] = fmaxf(v, 0.f);
    }
}

// ---------------- conv2: out = (conv3x3(h, w2) + b2) * S + HSI ----------------
__global__ __launch_bounds__(256) void conv2_kernel(const float* __restrict__ hbuf,
                                                    const float* __restrict__ HSI,
                                                    const float* __restrict__ Sv,
                                                    const float* __restrict__ w2,
                                                    const float* __restrict__ b2,
                                                    float* __restrict__ out) {
    __shared__ __align__(16) float wl[CC][9][COG];
    const int tid = threadIdx.x;
    const int co0 = blockIdx.y * COG;
    for (int idx = tid; idx < CC * 9 * COG; idx += 256) {
        int cog = idx & (COG - 1);
        int rest = idx >> 3;
        int cin = rest / 9, tap = rest - cin * 9;
        wl[cin][tap][cog] = w2[(co0 + cog) * (CC * 9) + cin * 9 + tap];
    }
    __syncthreads();
    const int g = blockIdx.x * 256 + tid;
    const int b = g / LL, l = g - b * LL;
    const int y = div80(l), x = l - y * 80;
    float acc[COG];
    #pragma unroll
    for (int i = 0; i < COG; ++i) acc[i] = 0.f;
    for (int cin = 0; cin < CC; ++cin) {
        const float* img = hbuf + (size_t)(b * CC + cin) * LL;
        float tap[9];
        #pragma unroll
        for (int i = 0; i < 3; ++i)
            #pragma unroll
            for (int j = 0; j < 3; ++j) {
                int yy = y + i - 1, xx = x + j - 1;
                tap[i * 3 + j] = ((unsigned)yy < 80u && (unsigned)xx < 80u) ? img[yy * 80 + xx] : 0.f;
            }
        #pragma unroll
        for (int t9 = 0; t9 < 9; ++t9) {
            const float4 wa = *reinterpret_cast<const float4*>(&wl[cin][t9][0]);
            const float4 wb = *reinterpret_cast<const float4*>(&wl[cin][t9][4]);
            acc[0] = fmaf(tap[t9], wa.x, acc[0]);
            acc[1] = fmaf(tap[t9], wa.y, acc[1]);
            acc[2] = fmaf(tap[t9], wa.z, acc[2]);
            acc[3] = fmaf(tap[t9], wa.w, acc[3]);
            acc[4] = fmaf(tap[t9], wb.x, acc[4]);
            acc[5] = fmaf(tap[t9], wb.y, acc[5]);
            acc[6] = fmaf(tap[t9], wb.z, acc[6]);
            acc[7] = fmaf(tap[t9], wb.w, acc[7]);
        }
    }
    const float s = Sv[b * LL + l];
    #pragma unroll
    for (int cog = 0; cog < COG; ++cog) {
        int c = co0 + cog;
        out[(size_t)(b * CC + c) * LL + l] = fmaf(acc[cog] + b2[c], s, HSI[(size_t)(b * CC + c) * LL + l]);
    }
}

extern "C" void kernel_launch(void* const* d_in, const int* in_sizes, int n_in,
                              void* d_out, int out_size, void* d_ws, size_t ws_size,
                              hipStream_t stream) {
    const float* HSI = (const float*)d_in[0];
    const float* PAN = (const float*)d_in[1];
    const float* w1  = (const float*)d_in[2];
    const float* b1  = (const float*)d_in[3];
    const float* w2  = (const float*)d_in[4];
    const float* b2  = (const float*)d_in[5];
    float* out = (float*)d_out;

    char* ws = (char*)d_ws;
    size_t off = 0;
    auto alloc = [&](size_t bytes) -> void* {
        void* p = ws + off;
        off += (bytes + 255) & ~(size_t)255;
        return p;
    };
    float* partH = (float*)alloc((size_t)BB * CC * LL * 4);
    float* partP = (float*)alloc((size_t)BB * CC * LL * 4);
    float* invH  = (float*)alloc((size_t)BB * LL * 4);
    float* invP  = (float*)alloc((size_t)BB * LL * 4);
    char*  Apack = (char*) alloc((size_t)BB * 3 * LL * 256);
    char*  Bpack = (char*) alloc((size_t)BB * 3 * LL * 256);
    __half* tileMax8 = (__half*)alloc((size_t)BB * LL * NT8 * 2);  // 20.5 MB
    float* Sv    = (float*)alloc((size_t)BB * LL * 4);
    int*   Sa    = (int*)  alloc((size_t)BB * LL * 4);
    // partH/partP are dead after prep2 -> reuse their space for T/hbuf
    float* T     = partH;
    float* hbuf  = partP;

    prep1_kernel<<<dim3((BB * CC * LL + 255) / 256), 256, 0, stream>>>(HSI, PAN, partH, partP);
    prep2_kernel<<<dim3((BB * LL + 255) / 256), 256, 0, stream>>>(partH, partP, invH, invP);
    pack_kernel<<<dim3((BB * 2 * LL * 36 + 255) / 256), 256, 0, stream>>>(HSI, PAN, invH, invP, Apack, Bpack);
    simq_kernel<<<dim3(500), 256, 0, stream>>>(Apack, Bpack, tileMax8);
    scanfix_kernel<<<dim3(BB * LL / 4), 256, 0, stream>>>(HSI, PAN, invH, invP, tileMax8, Sv, Sa);
    tfold_kernel<<<dim3((BB * CC * LL + 255) / 256), 256, 0, stream>>>(PAN, Sa, T);
    conv1_kernel<<<dim3(BB * LL / 256, CC / COG), 256, 0, stream>>>(T, HSI, w1, b1, hbuf);
    conv2_kernel<<<dim3(BB * LL / 256, CC / COG), 256, 0, stream>>>(hbuf, HSI, Sv, w2, b2, out);
}

// Round 6
// 247.814 us; speedup vs baseline: 6.0382x; 1.1780x over previous
//
#include <hip/hip_runtime.h>
#include <hip/hip_bf16.h>
#include <hip/hip_fp16.h>
#include <stdint.h>

#define HH 80
#define WW 80
#define LL 6400
#define CC 32
#define BB 2
#define COG 16
#define DELTA 0.011f
#define NT8 800

typedef __bf16 bf16x8 __attribute__((ext_vector_type(8)));
typedef float  f32x4  __attribute__((ext_vector_type(4)));

__device__ __forceinline__ int div80(int v) {
    return (int)(((unsigned)v * 52429u) >> 22);   // exact for 0 <= v < 52428
}

__device__ __forceinline__ unsigned short f2bf(float f) {
    unsigned int u = __float_as_uint(f);
    return (unsigned short)((u + 0x7fffu + ((u >> 16) & 1u)) >> 16);   // RNE
}

__device__ __forceinline__ void gload_lds16(void* g, void* l) {
    __builtin_amdgcn_global_load_lds(
        (__attribute__((address_space(1))) void*)g,
        (__attribute__((address_space(3))) void*)l, 16, 0, 0);
}

// ---------------- prep1: per-(b,c,l) 3x3 squared-sums ----------------
__global__ void prep1_kernel(const float* __restrict__ HSI, const float* __restrict__ PAN,
                             float* __restrict__ partH, float* __restrict__ partP) {
    int g = blockIdx.x * 256 + threadIdx.x;          // (b*CC + c)*LL + l
    if (g >= BB * CC * LL) return;
    int l = g % LL;
    int y = div80(l), x = l - y * 80;
    const float* hc = HSI + (size_t)(g - l);
    const float* pc = PAN + (size_t)(g - l);
    float sh = 0.f, sp = 0.f;
    #pragma unroll
    for (int i = 0; i < 3; ++i) {
        int yy = y + i - 1;
        if ((unsigned)yy >= 80u) continue;
        #pragma unroll
        for (int j = 0; j < 3; ++j) {
            int xx = x + j - 1;
            if ((unsigned)xx >= 80u) continue;
            float hv = hc[yy * 80 + xx]; sh = fmaf(hv, hv, sh);
            float pv = pc[yy * 80 + xx]; sp = fmaf(pv, pv, sp);
        }
    }
    partH[g] = sh;
    partP[g] = sp;
}

// ---------------- prep2: reduce over channels -> inverse norms ----------------
__global__ void prep2_kernel(const float* __restrict__ partH, const float* __restrict__ partP,
                             float* __restrict__ invH, float* __restrict__ invP) {
    int g = blockIdx.x * 256 + threadIdx.x;          // b*LL + l
    if (g >= BB * LL) return;
    int b = g / LL, l = g - b * LL;
    float sh = 0.f, sp = 0.f;
    #pragma unroll
    for (int c = 0; c < CC; ++c) {
        sh += partH[((size_t)(b * CC + c)) * LL + l];
        sp += partP[((size_t)(b * CC + c)) * LL + l];
    }
    invH[g] = 1.f / fmaxf(sqrtf(sh), 1e-12f);
    invP[g] = 1.f / fmaxf(sqrtf(sp), 1e-12f);
}

// ---------------- pack: bf16 packs (normalized, swizzled) + fp32 unfold (raw) ----------------
__global__ void pack_kernel(const float* __restrict__ HSI, const float* __restrict__ PAN,
                            const float* __restrict__ invH, const float* __restrict__ invP,
                            char* __restrict__ Apack, char* __restrict__ Bpack,
                            float* __restrict__ PANunf, float* __restrict__ HSIunf) {
    int t = blockIdx.x * 256 + threadIdx.x;
    if (t >= BB * 2 * LL * 36) return;
    int g = t % 36;
    int rest = t / 36;
    int l = rest % LL; rest /= LL;
    int mat = rest & 1;      // 0 = PAN (A operand), 1 = HSI (B operand)
    int b = rest >> 1;
    const float* img = (mat ? HSI : PAN) + (size_t)b * CC * LL;
    float inv = (mat ? invH : invP)[b * LL + l];
    int y = div80(l), x = l - y * 80;
    int k0 = g * 8;
    int c = k0 / 9, tap = k0 - c * 9;
    unsigned short hs[8];
    float raw[8];
    #pragma unroll
    for (int j = 0; j < 8; ++j) {
        int t3 = tap / 3;
        int dy = t3 - 1, dx = tap - t3 * 3 - 1;
        int yy = y + dy, xx = x + dx;
        float rv = ((unsigned)yy < 80u && (unsigned)xx < 80u)
                       ? img[(size_t)c * LL + yy * 80 + xx] : 0.f;
        raw[j] = rv;
        hs[j] = f2bf(rv * inv);
        if (++tap == 9) { tap = 0; ++c; }
    }
    // fp32 unfold store (raw values, k-order)
    float* unf = (mat ? HSIunf : PANunf) + ((size_t)b * LL + l) * 288 + k0;
    float4 r0 = {raw[0], raw[1], raw[2], raw[3]};
    float4 r1 = {raw[4], raw[5], raw[6], raw[7]};
    *(float4*)(unf)     = r0;
    *(float4*)(unf + 4) = r1;
    // bf16 pack store
    char* pk = mat ? Bpack : Apack;
    int slot = (g % 12) ^ (l & 15);
    int q = g / 12;
    size_t off = ((size_t)(b * 3 + q) * LL + l) * 256 + slot * 16;
    uint4 hv;
    hv.x = hs[0] | ((unsigned)hs[1] << 16); hv.y = hs[2] | ((unsigned)hs[3] << 16);
    hv.z = hs[4] | ((unsigned)hs[5] << 16); hv.w = hs[6] | ((unsigned)hs[7] << 16);
    *(uint4*)(pk + off) = hv;
}

// ---------------- simq: MFMA similarity (hi-only, K=288), per-(8l-subtile, m) max ----------------
__global__ __launch_bounds__(256) void simq_kernel(const char* __restrict__ Apack,
                                                   const char* __restrict__ Bpack,
                                                   __half* __restrict__ tileMax8) {
    __shared__ __align__(16) char Alds[32768];
    __shared__ __align__(16) char Blds[32768];
    // bijective XCD swizzle for nwg=500: q=62, r=4
    const int orig = blockIdx.x;
    const int xcd = orig & 7, idx = orig >> 3;
    const int wg = (xcd < 4 ? xcd * 63 : 252 + (xcd - 4) * 62) + idx;
    const int b = wg / 250;
    int rest = wg - b * 250;
    const int sp = rest / 50;
    const int mt = rest - sp * 50;

    const int tid = threadIdx.x;
    const int lane = tid & 63, w = tid >> 6;
    const int wl = w >> 1, wm = w & 1;
    const int r15 = lane & 15, h = lane >> 4;
    const char* Ab = Apack + (size_t)b * 3 * LL * 256;
    const char* Bb = Bpack + (size_t)b * 3 * LL * 256;
    const int m0 = mt * 128;
    const f32x4 fzero = {0.f, 0.f, 0.f, 0.f};

    #pragma unroll 1
    for (int lt = 0; lt < 10; ++lt) {
        const int l0 = (sp * 10 + lt) * 128;
        f32x4 acc[4][4];
        #pragma unroll
        for (int i = 0; i < 4; ++i)
            #pragma unroll
            for (int j = 0; j < 4; ++j) acc[i][j] = fzero;

        #pragma unroll 1
        for (int c = 0; c < 3; ++c) {
            __syncthreads();
            const char* gA = Ab + ((size_t)c * LL + l0) * 256 + w * 8192 + lane * 16;
            const char* gB = Bb + ((size_t)c * LL + m0) * 256 + w * 8192 + lane * 16;
            char* lA = Alds + w * 8192;
            char* lB = Blds + w * 8192;
            #pragma unroll
            for (int i = 0; i < 8; ++i) {
                gload_lds16((void*)(gA + i * 1024), lA + i * 1024);
                gload_lds16((void*)(gB + i * 1024), lB + i * 1024);
            }
            __syncthreads();
            #pragma unroll
            for (int ks = 0; ks < 3; ++ks) {
                const int gp = ((ks * 4 + h) ^ r15) * 16;
                bf16x8 af[4], bfr[4];
                #pragma unroll
                for (int f = 0; f < 4; ++f) {
                    af[f]  = *(const bf16x8*)(Alds + (wl * 64 + f * 16 + r15) * 256 + gp);
                    bfr[f] = *(const bf16x8*)(Blds + (wm * 64 + f * 16 + r15) * 256 + gp);
                }
                #pragma unroll
                for (int fl = 0; fl < 4; ++fl)
                    #pragma unroll
                    for (int fm = 0; fm < 4; ++fm)
                        acc[fl][fm] = __builtin_amdgcn_mfma_f32_16x16x32_bf16(
                            af[fl], bfr[fm], acc[fl][fm], 0, 0, 0);
            }
        }
        // fold: per m-col max over each 8-l subtile; C layout row = h*4 + reg
        const int Tbase = (sp * 10 + lt) * 16 + wl * 8;
        #pragma unroll
        for (int fl = 0; fl < 4; ++fl) {
            #pragma unroll
            for (int fm = 0; fm < 4; ++fm) {
                f32x4 a = acc[fl][fm];
                float v = fmaxf(fmaxf(a[0], a[1]), fmaxf(a[2], a[3]));
                v = fmaxf(v, __shfl_xor(v, 16, 64));
                if ((h & 1) == 0) {
                    const int m = m0 + wm * 64 + fm * 16 + r15;
                    tileMax8[((size_t)b * LL + m) * NT8 + Tbase + fl * 2 + (h >> 1)] = __float2half(v);
                }
            }
        }
    }
}

// ---------------- scanfix v4: wave-per-(b,m), coalesced unfold rescore ----------------
// lane = (lql = l within 8-subtile) x (kq = k-octant of 36 contiguous k)
__global__ __launch_bounds__(256) void scanfix_kernel(const float* __restrict__ PANunf,
                                                      const float* __restrict__ HSIunf,
                                                      const float* __restrict__ invH,
                                                      const float* __restrict__ invP,
                                                      const __half* __restrict__ tileMax8,
                                                      float* __restrict__ Sv, int* __restrict__ Sa) {
    const int gw = blockIdx.x * 4 + (threadIdx.x >> 6);   // b*LL + m
    const int lane = threadIdx.x & 63;
    const int b = gw / LL;
    const __half* tm = tileMax8 + (size_t)gw * NT8;

    float tv[13];
    #pragma unroll
    for (int i = 0; i < 13; ++i) {
        int T = i * 64 + lane;
        tv[i] = (T < NT8) ? __half2float(tm[T]) : -3.0e38f;
    }
    float v1 = tv[0];
    #pragma unroll
    for (int i = 1; i < 13; ++i) v1 = fmaxf(v1, tv[i]);
    #pragma unroll
    for (int d = 1; d < 64; d <<= 1) v1 = fmaxf(v1, __shfl_xor(v1, d, 64));
    const float th = v1 - DELTA;

    const float ihm = invH[gw];
    const int lql = lane >> 3, kq = lane & 7;

    // hoisted HSI column slice: 36 contiguous floats (coalesced, lql-broadcast)
    float hreg[36];
    {
        const float4* hv4 = (const float4*)(HSIunf + (size_t)gw * 288 + kq * 36);
        #pragma unroll
        for (int j = 0; j < 9; ++j) {
            float4 v = hv4[j];
            hreg[j * 4 + 0] = v.x; hreg[j * 4 + 1] = v.y;
            hreg[j * 4 + 2] = v.z; hreg[j * 4 + 3] = v.w;
        }
    }

    float bv = -3.0e38f; int bl = 0x7fffffff;

    #pragma unroll 1
    for (int i = 0; i < 13; ++i) {
        unsigned long long mask = __ballot(tv[i] >= th);
        while (mask) {
            const int t = __ffsll((long long)mask) - 1;
            mask &= mask - 1;
            const int T = i * 64 + t;
            const int l = T * 8 + lql;
            const float4* pv4 = (const float4*)(PANunf + ((size_t)b * LL + l) * 288 + kq * 36);
            float part = 0.f;
            #pragma unroll
            for (int j = 0; j < 9; ++j) {
                float4 p = pv4[j];
                part = fmaf(p.x, hreg[j * 4 + 0], part);
                part = fmaf(p.y, hreg[j * 4 + 1], part);
                part = fmaf(p.z, hreg[j * 4 + 2], part);
                part = fmaf(p.w, hreg[j * 4 + 3], part);
            }
            // reduce over kq (lane bits 0..2)
            part += __shfl_xor(part, 1, 64);
            part += __shfl_xor(part, 2, 64);
            part += __shfl_xor(part, 4, 64);
            const float val = part * invP[b * LL + l] * ihm;
            if (val > bv || (val == bv && l < bl)) { bv = val; bl = l; }
        }
    }
    // wave reduce with first-max tie rule
    #pragma unroll
    for (int d = 1; d < 64; d <<= 1) {
        float ov = __shfl_xor(bv, d, 64);
        int   ol = __shfl_xor(bl, d, 64);
        if (ov > bv || (ov == bv && ol < bl)) { bv = ov; bl = ol; }
    }
    if (lane == 0) { Sv[gw] = bv; Sa[gw] = bl; }
}

// ---------------- T_lv3 = fold3x3(gathered PAN patches) / 9 ----------------
__global__ void tfold_kernel(const float* __restrict__ PAN, const int* __restrict__ Sa,
                             float* __restrict__ T) {
    int g = blockIdx.x * blockDim.x + threadIdx.x;
    if (g >= BB * CC * LL) return;
    int bc = g / LL, l = g - bc * LL;
    int b = bc >> 5;
    int y = div80(l), x = l - y * 80;
    const float* img = PAN + (size_t)bc * LL;
    const int* Sab = Sa + b * LL;
    float acc = 0.f;
    #pragma unroll
    for (int i = 0; i < 3; ++i) {
        int yp = y + 1 - i;
        if ((unsigned)yp >= 80u) continue;
        #pragma unroll
        for (int j = 0; j < 3; ++j) {
            int xp = x + 1 - j;
            if ((unsigned)xp >= 80u) continue;
            int a = Sab[yp * 80 + xp];
            int ya = div80(a), xa = a - ya * 80;
            int py = ya + i - 1, px = xa + j - 1;
            if ((unsigned)py < 80u && (unsigned)px < 80u) acc += img[py * 80 + px];
        }
    }
    T[g] = acc * (1.f / 9.f);
}

// ---------------- conv1: h = relu(conv3x3(concat(T,HSI), w1) + b1) ----------------
__global__ __launch_bounds__(256) void conv1_kernel(const float* __restrict__ T,
                                                    const float* __restrict__ HSI,
                                                    const float* __restrict__ w1,
                                                    const float* __restrict__ b1,
                                                    float* __restrict__ h) {
    __shared__ __align__(16) float wl[64][9][COG];   // 36.9 KB
    const int tid = threadIdx.x;
    const int co0 = blockIdx.y * COG;
    for (int idx = tid; idx < 64 * 9 * COG; idx += 256) {
        int cog = idx & (COG - 1);
        int rest = idx >> 4;
        int cin = rest / 9, tap = rest - cin * 9;
        wl[cin][tap][cog] = w1[(co0 + cog) * (64 * 9) + cin * 9 + tap];
    }
    __syncthreads();
    const int g = blockIdx.x * 256 + tid;
    const int b = g / LL, l = g - b * LL;
    const int y = div80(l), x = l - y * 80;
    float acc[COG];
    #pragma unroll
    for (int i = 0; i < COG; ++i) acc[i] = 0.f;
    for (int cin = 0; cin < 64; ++cin) {
        const float* img = (cin < CC) ? (T + (size_t)(b * CC + cin) * LL)
                                      : (HSI + (size_t)(b * CC + (cin - CC)) * LL);
        float tap[9];
        #pragma unroll
        for (int i = 0; i < 3; ++i)
            #pragma unroll
            for (int j = 0; j < 3; ++j) {
                int yy = y + i - 1, xx = x + j - 1;
                tap[i * 3 + j] = ((unsigned)yy < 80u && (unsigned)xx < 80u) ? img[yy * 80 + xx] : 0.f;
            }
        #pragma unroll
        for (int t9 = 0; t9 < 9; ++t9) {
            #pragma unroll
            for (int q4 = 0; q4 < COG / 4; ++q4) {
                const float4 wv = *reinterpret_cast<const float4*>(&wl[cin][t9][q4 * 4]);
                acc[q4 * 4 + 0] = fmaf(tap[t9], wv.x, acc[q4 * 4 + 0]);
                acc[q4 * 4 + 1] = fmaf(tap[t9], wv.y, acc[q4 * 4 + 1]);
                acc[q4 * 4 + 2] = fmaf(tap[t9], wv.z, acc[q4 * 4 + 2]);
                acc[q4 * 4 + 3] = fmaf(tap[t9], wv.w, acc[q4 * 4 + 3]);
            }
        }
    }
    #pragma unroll
    for (int cog = 0; cog < COG; ++cog) {
        float v = acc[cog] + b1[co0 + cog];
        h[(size_t)(b * CC + co0 + cog) * LL + l] = fmaxf(v, 0.f);
    }
}

// ---------------- conv2: out = (conv3x3(h, w2) + b2) * S + HSI ----------------
__global__ __launch_bounds__(256) void conv2_kernel(const float* __restrict__ hbuf,
                                                    const float* __restrict__ HSI,
                                                    const float* __restrict__ Sv,
                                                    const float* __restrict__ w2,
                                                    const float* __restrict__ b2,
                                                    float* __restrict__ out) {
    __shared__ __align__(16) float wl[CC][9][COG];   // 18.4 KB
    const int tid = threadIdx.x;
    const int co0 = blockIdx.y * COG;
    for (int idx = tid; idx < CC * 9 * COG; idx += 256) {
        int cog = idx & (COG - 1);
        int rest = idx >> 4;
        int cin = rest / 9, tap = rest - cin * 9;
        wl[cin][tap][cog] = w2[(co0 + cog) * (CC * 9) + cin * 9 + tap];
    }
    __syncthreads();
    const int g = blockIdx.x * 256 + tid;
    const int b = g / LL, l = g - b * LL;
    const int y = div80(l), x = l - y * 80;
    float acc[COG];
    #pragma unroll
    for (int i = 0; i < COG; ++i) acc[i] = 0.f;
    for (int cin = 0; cin < CC; ++cin) {
        const float* img = hbuf + (size_t)(b * CC + cin) * LL;
        float tap[9];
        #pragma unroll
        for (int i = 0; i < 3; ++i)
            #pragma unroll
            for (int j = 0; j < 3; ++j) {
                int yy = y + i - 1, xx = x + j - 1;
                tap[i * 3 + j] = ((unsigned)yy < 80u && (unsigned)xx < 80u) ? img[yy * 80 + xx] : 0.f;
            }
        #pragma unroll
        for (int t9 = 0; t9 < 9; ++t9) {
            #pragma unroll
            for (int q4 = 0; q4 < COG / 4; ++q4) {
                const float4 wv = *reinterpret_cast<const float4*>(&wl[cin][t9][q4 * 4]);
                acc[q4 * 4 + 0] = fmaf(tap[t9], wv.x, acc[q4 * 4 + 0]);
                acc[q4 * 4 + 1] = fmaf(tap[t9], wv.y, acc[q4 * 4 + 1]);
                acc[q4 * 4 + 2] = fmaf(tap[t9], wv.z, acc[q4 * 4 + 2]);
                acc[q4 * 4 + 3] = fmaf(tap[t9], wv.w, acc[q4 * 4 + 3]);
            }
        }
    }
    const float s = Sv[b * LL + l];
    #pragma unroll
    for (int cog = 0; cog < COG; ++cog) {
        int c = co0 + cog;
        out[(size_t)(b * CC + c) * LL + l] = fmaf(acc[cog] + b2[c], s, HSI[(size_t)(b * CC + c) * LL + l]);
    }
}

extern "C" void kernel_launch(void* const* d_in, const int* in_sizes, int n_in,
                              void* d_out, int out_size, void* d_ws, size_t ws_size,
                              hipStream_t stream) {
    const float* HSI = (const float*)d_in[0];
    const float* PAN = (const float*)d_in[1];
    const float* w1  = (const float*)d_in[2];
    const float* b1  = (const float*)d_in[3];
    const float* w2  = (const float*)d_in[4];
    const float* b2  = (const float*)d_in[5];
    float* out = (float*)d_out;

    char* ws = (char*)d_ws;
    size_t off = 0;
    auto alloc = [&](size_t bytes) -> void* {
        void* p = ws + off;
        off += (bytes + 255) & ~(size_t)255;
        return p;
    };
    float* partH = (float*)alloc((size_t)BB * CC * LL * 4);    // 1.64 MB
    float* partP = (float*)alloc((size_t)BB * CC * LL * 4);    // 1.64 MB
    float* invH  = (float*)alloc((size_t)BB * LL * 4);
    float* invP  = (float*)alloc((size_t)BB * LL * 4);
    char*  Apack = (char*) alloc((size_t)BB * 3 * LL * 256);   // 9.83 MB
    char*  Bpack = (char*) alloc((size_t)BB * 3 * LL * 256);   // 9.83 MB
    __half* tileMax8 = (__half*)alloc((size_t)BB * LL * NT8 * 2);    // 20.5 MB
    float* PANunf = (float*)alloc((size_t)BB * LL * 288 * 4);  // 14.75 MB
    float* HSIunf = (float*)alloc((size_t)BB * LL * 288 * 4);  // 14.75 MB
    float* Sv    = (float*)alloc((size_t)BB * LL * 4);
    int*   Sa    = (int*)  alloc((size_t)BB * LL * 4);
    // partH/partP are dead after prep2 -> reuse their space for T/hbuf
    float* T     = partH;
    float* hbuf  = partP;

    prep1_kernel<<<dim3((BB * CC * LL + 255) / 256), 256, 0, stream>>>(HSI, PAN, partH, partP);
    prep2_kernel<<<dim3((BB * LL + 255) / 256), 256, 0, stream>>>(partH, partP, invH, invP);
    pack_kernel<<<dim3((BB * 2 * LL * 36 + 255) / 256), 256, 0, stream>>>(HSI, PAN, invH, invP,
                                                                          Apack, Bpack, PANunf, HSIunf);
    simq_kernel<<<dim3(500), 256, 0, stream>>>(Apack, Bpack, tileMax8);
    scanfix_kernel<<<dim3(BB * LL / 4), 256, 0, stream>>>(PANunf, HSIunf, invH, invP, tileMax8, Sv, Sa);
    tfold_kernel<<<dim3((BB * CC * LL + 255) / 256), 256, 0, stream>>>(PAN, Sa, T);
    conv1_kernel<<<dim3(BB * LL / 256, CC / COG), 256, 0, stream>>>(T, HSI, w1, b1, hbuf);
    conv2_kernel<<<dim3(BB * LL / 256, CC / COG), 256, 0, stream>>>(hbuf, HSI, Sv, w2, b2, out);
}

// Round 7
// 226.808 us; speedup vs baseline: 6.5974x; 1.0926x over previous
//
#include <hip/hip_runtime.h>
#include <hip/hip_bf16.h>
#include <hip/hip_fp16.h>
#include <stdint.h>

#define HH 80
#define WW 80
#define LL 6400
#define CC 32
#define BB 2
#define COG 16
#define DELTA 0.011f
#define NT8 800

typedef __bf16 bf16x8 __attribute__((ext_vector_type(8)));
typedef float  f32x4  __attribute__((ext_vector_type(4)));

__device__ __forceinline__ int div80(int v) {
    return (int)(((unsigned)v * 52429u) >> 22);   // exact for 0 <= v < 52428
}

__device__ __forceinline__ unsigned short f2bf(float f) {
    unsigned int u = __float_as_uint(f);
    return (unsigned short)((u + 0x7fffu + ((u >> 16) & 1u)) >> 16);   // RNE
}

__device__ __forceinline__ void gload_lds16(void* g, void* l) {
    __builtin_amdgcn_global_load_lds(
        (__attribute__((address_space(1))) void*)g,
        (__attribute__((address_space(3))) void*)l, 16, 0, 0);
}

// ---------------- prep1: per-(b,c,l) 3x3 squared-sums ----------------
__global__ void prep1_kernel(const float* __restrict__ HSI, const float* __restrict__ PAN,
                             float* __restrict__ partH, float* __restrict__ partP) {
    int g = blockIdx.x * 256 + threadIdx.x;          // (b*CC + c)*LL + l
    if (g >= BB * CC * LL) return;
    int l = g % LL;
    int y = div80(l), x = l - y * 80;
    const float* hc = HSI + (size_t)(g - l);
    const float* pc = PAN + (size_t)(g - l);
    float sh = 0.f, sp = 0.f;
    #pragma unroll
    for (int i = 0; i < 3; ++i) {
        int yy = y + i - 1;
        if ((unsigned)yy >= 80u) continue;
        #pragma unroll
        for (int j = 0; j < 3; ++j) {
            int xx = x + j - 1;
            if ((unsigned)xx >= 80u) continue;
            float hv = hc[yy * 80 + xx]; sh = fmaf(hv, hv, sh);
            float pv = pc[yy * 80 + xx]; sp = fmaf(pv, pv, sp);
        }
    }
    partH[g] = sh;
    partP[g] = sp;
}

// ---------------- prep2: reduce over channels -> inverse norms ----------------
__global__ void prep2_kernel(const float* __restrict__ partH, const float* __restrict__ partP,
                             float* __restrict__ invH, float* __restrict__ invP) {
    int g = blockIdx.x * 256 + threadIdx.x;          // b*LL + l
    if (g >= BB * LL) return;
    int b = g / LL, l = g - b * LL;
    float sh = 0.f, sp = 0.f;
    #pragma unroll
    for (int c = 0; c < CC; ++c) {
        sh += partH[((size_t)(b * CC + c)) * LL + l];
        sp += partP[((size_t)(b * CC + c)) * LL + l];
    }
    invH[g] = 1.f / fmaxf(sqrtf(sh), 1e-12f);
    invP[g] = 1.f / fmaxf(sqrtf(sp), 1e-12f);
}

// ---------------- pack: bf16 packs (normalized, swizzled) + fp32 unfold (raw) ----------------
__global__ void pack_kernel(const float* __restrict__ HSI, const float* __restrict__ PAN,
                            const float* __restrict__ invH, const float* __restrict__ invP,
                            char* __restrict__ Apack, char* __restrict__ Bpack,
                            float* __restrict__ PANunf, float* __restrict__ HSIunf) {
    int t = blockIdx.x * 256 + threadIdx.x;
    if (t >= BB * 2 * LL * 36) return;
    int g = t % 36;
    int rest = t / 36;
    int l = rest % LL; rest /= LL;
    int mat = rest & 1;      // 0 = PAN (A operand), 1 = HSI (B operand)
    int b = rest >> 1;
    const float* img = (mat ? HSI : PAN) + (size_t)b * CC * LL;
    float inv = (mat ? invH : invP)[b * LL + l];
    int y = div80(l), x = l - y * 80;
    int k0 = g * 8;
    int c = k0 / 9, tap = k0 - c * 9;
    unsigned short hs[8];
    float raw[8];
    #pragma unroll
    for (int j = 0; j < 8; ++j) {
        int t3 = tap / 3;
        int dy = t3 - 1, dx = tap - t3 * 3 - 1;
        int yy = y + dy, xx = x + dx;
        float rv = ((unsigned)yy < 80u && (unsigned)xx < 80u)
                       ? img[(size_t)c * LL + yy * 80 + xx] : 0.f;
        raw[j] = rv;
        hs[j] = f2bf(rv * inv);
        if (++tap == 9) { tap = 0; ++c; }
    }
    // fp32 unfold store (raw values, k-order)
    float* unf = (mat ? HSIunf : PANunf) + ((size_t)b * LL + l) * 288 + k0;
    float4 r0 = {raw[0], raw[1], raw[2], raw[3]};
    float4 r1 = {raw[4], raw[5], raw[6], raw[7]};
    *(float4*)(unf)     = r0;
    *(float4*)(unf + 4) = r1;
    // bf16 pack store
    char* pk = mat ? Bpack : Apack;
    int slot = (g % 12) ^ (l & 15);
    int q = g / 12;
    size_t off = ((size_t)(b * 3 + q) * LL + l) * 256 + slot * 16;
    uint4 hv;
    hv.x = hs[0] | ((unsigned)hs[1] << 16); hv.y = hs[2] | ((unsigned)hs[3] << 16);
    hv.z = hs[4] | ((unsigned)hs[5] << 16); hv.w = hs[6] | ((unsigned)hs[7] << 16);
    *(uint4*)(pk + off) = hv;
}

// ---------------- simq: MFMA similarity (hi-only, K=288), B-frags register-resident ----------------
// Block = (b, sp, mt): 128 m cols resident; loops 10 l-tiles of 128.
// 4 waves (2l x 2m), wave tile 64x64, mfma_f32_16x16x32_bf16.
// B fragments (36 x bf16x8 = 144 VGPR) loaded global->reg ONCE; LDS = A double-buffer only.
__global__ __launch_bounds__(256, 2) void simq_kernel(const char* __restrict__ Apack,
                                                      const char* __restrict__ Bpack,
                                                      __half* __restrict__ tileMax8) {
    __shared__ __align__(16) char Alds[2][32768];
    // bijective XCD swizzle for nwg=500: q=62, r=4
    const int orig = blockIdx.x;
    const int xcd = orig & 7, idx = orig >> 3;
    const int wg = (xcd < 4 ? xcd * 63 : 252 + (xcd - 4) * 62) + idx;
    const int b = wg / 250;
    int rest = wg - b * 250;
    const int sp = rest / 50;
    const int mt = rest - sp * 50;

    const int tid = threadIdx.x;
    const int lane = tid & 63, w = tid >> 6;
    const int wl = w >> 1, wm = w & 1;
    const int r15 = lane & 15, h = lane >> 4;
    const char* Ab = Apack + (size_t)b * 3 * LL * 256;
    const char* Bb = Bpack + (size_t)b * 3 * LL * 256;
    const int m0 = mt * 128;
    const f32x4 fzero = {0.f, 0.f, 0.f, 0.f};

    // ---- B fragments: load once, keep in registers across all l-tiles ----
    bf16x8 bq[3][3][4];
    {
        const int rowb = m0 + wm * 64 + r15;
        #pragma unroll
        for (int c = 0; c < 3; ++c)
            #pragma unroll
            for (int ks = 0; ks < 3; ++ks)
                #pragma unroll
                for (int fm = 0; fm < 4; ++fm) {
                    const int gp = ((ks * 4 + h) ^ r15) * 16;
                    bq[c][ks][fm] = *(const bf16x8*)(Bb + ((size_t)c * LL + rowb + fm * 16) * 256 + gp);
                }
    }

    // ---- prologue: stage A for step 0 (lt=0, c=0) ----
    {
        const char* gA = Ab + ((size_t)(sp * 10) * 128) * 256 + w * 8192 + lane * 16;
        char* lA = Alds[0] + w * 8192;
        #pragma unroll
        for (int i = 0; i < 8; ++i) gload_lds16((void*)(gA + i * 1024), lA + i * 1024);
    }
    __syncthreads();

    int cur = 0;
    #pragma unroll 1
    for (int lt = 0; lt < 10; ++lt) {
        f32x4 acc[4][4];
        #pragma unroll
        for (int i = 0; i < 4; ++i)
            #pragma unroll
            for (int j = 0; j < 4; ++j) acc[i][j] = fzero;

        #pragma unroll
        for (int c = 0; c < 3; ++c) {
            // prefetch next (lt,c) step into the other buffer
            if (c < 2 || lt < 9) {
                const int lt2 = (c == 2) ? lt + 1 : lt;
                const int c2  = (c == 2) ? 0 : c + 1;
                const int l0n = (sp * 10 + lt2) * 128;
                const char* gA = Ab + ((size_t)c2 * LL + l0n) * 256 + w * 8192 + lane * 16;
                char* lA = Alds[cur ^ 1] + w * 8192;
                #pragma unroll
                for (int i = 0; i < 8; ++i) gload_lds16((void*)(gA + i * 1024), lA + i * 1024);
            }
            // compute from current buffer
            const char* lAr = Alds[cur];
            #pragma unroll
            for (int ks = 0; ks < 3; ++ks) {
                const int gp = ((ks * 4 + h) ^ r15) * 16;
                bf16x8 af[4];
                #pragma unroll
                for (int f = 0; f < 4; ++f)
                    af[f] = *(const bf16x8*)(lAr + (wl * 64 + f * 16 + r15) * 256 + gp);
                #pragma unroll
                for (int fl = 0; fl < 4; ++fl)
                    #pragma unroll
                    for (int fm = 0; fm < 4; ++fm)
                        acc[fl][fm] = __builtin_amdgcn_mfma_f32_16x16x32_bf16(
                            af[fl], bq[c][ks][fm], acc[fl][fm], 0, 0, 0);
            }
            __syncthreads();
            cur ^= 1;
        }

        // fold: per m-col max over each 8-l subtile; C layout row = h*4 + reg
        const int Tbase = (sp * 10 + lt) * 16 + wl * 8;
        #pragma unroll
        for (int fl = 0; fl < 4; ++fl) {
            #pragma unroll
            for (int fm = 0; fm < 4; ++fm) {
                f32x4 a = acc[fl][fm];
                float v = fmaxf(fmaxf(a[0], a[1]), fmaxf(a[2], a[3]));
                v = fmaxf(v, __shfl_xor(v, 16, 64));
                if ((h & 1) == 0) {
                    const int m = m0 + wm * 64 + fm * 16 + r15;
                    tileMax8[((size_t)b * LL + m) * NT8 + Tbase + fl * 2 + (h >> 1)] = __float2half(v);
                }
            }
        }
    }
}

// ---------------- scanfix v4: wave-per-(b,m), coalesced unfold rescore ----------------
// lane = (lql = l within 8-subtile) x (kq = k-octant of 36 contiguous k)
__global__ __launch_bounds__(256) void scanfix_kernel(const float* __restrict__ PANunf,
                                                      const float* __restrict__ HSIunf,
                                                      const float* __restrict__ invH,
                                                      const float* __restrict__ invP,
                                                      const __half* __restrict__ tileMax8,
                                                      float* __restrict__ Sv, int* __restrict__ Sa) {
    const int gw = blockIdx.x * 4 + (threadIdx.x >> 6);   // b*LL + m
    const int lane = threadIdx.x & 63;
    const int b = gw / LL;
    const __half* tm = tileMax8 + (size_t)gw * NT8;

    float tv[13];
    #pragma unroll
    for (int i = 0; i < 13; ++i) {
        int T = i * 64 + lane;
        tv[i] = (T < NT8) ? __half2float(tm[T]) : -3.0e38f;
    }
    float v1 = tv[0];
    #pragma unroll
    for (int i = 1; i < 13; ++i) v1 = fmaxf(v1, tv[i]);
    #pragma unroll
    for (int d = 1; d < 64; d <<= 1) v1 = fmaxf(v1, __shfl_xor(v1, d, 64));
    const float th = v1 - DELTA;

    const float ihm = invH[gw];
    const int lql = lane >> 3, kq = lane & 7;

    // hoisted HSI column slice: 36 contiguous floats (coalesced, lql-broadcast)
    float hreg[36];
    {
        const float4* hv4 = (const float4*)(HSIunf + (size_t)gw * 288 + kq * 36);
        #pragma unroll
        for (int j = 0; j < 9; ++j) {
            float4 v = hv4[j];
            hreg[j * 4 + 0] = v.x; hreg[j * 4 + 1] = v.y;
            hreg[j * 4 + 2] = v.z; hreg[j * 4 + 3] = v.w;
        }
    }

    float bv = -3.0e38f; int bl = 0x7fffffff;

    #pragma unroll 1
    for (int i = 0; i < 13; ++i) {
        unsigned long long mask = __ballot(tv[i] >= th);
        while (mask) {
            const int t = __ffsll((long long)mask) - 1;
            mask &= mask - 1;
            const int T = i * 64 + t;
            const int l = T * 8 + lql;
            const float4* pv4 = (const float4*)(PANunf + ((size_t)b * LL + l) * 288 + kq * 36);
            float part = 0.f;
            #pragma unroll
            for (int j = 0; j < 9; ++j) {
                float4 p = pv4[j];
                part = fmaf(p.x, hreg[j * 4 + 0], part);
                part = fmaf(p.y, hreg[j * 4 + 1], part);
                part = fmaf(p.z, hreg[j * 4 + 2], part);
                part = fmaf(p.w, hreg[j * 4 + 3], part);
            }
            // reduce over kq (lane bits 0..2)
            part += __shfl_xor(part, 1, 64);
            part += __shfl_xor(part, 2, 64);
            part += __shfl_xor(part, 4, 64);
            const float val = part * invP[b * LL + l] * ihm;
            if (val > bv || (val == bv && l < bl)) { bv = val; bl = l; }
        }
    }
    // wave reduce with first-max tie rule
    #pragma unroll
    for (int d = 1; d < 64; d <<= 1) {
        float ov = __shfl_xor(bv, d, 64);
        int   ol = __shfl_xor(bl, d, 64);
        if (ov > bv || (ov == bv && ol < bl)) { bv = ov; bl = ol; }
    }
    if (lane == 0) { Sv[gw] = bv; Sa[gw] = bl; }
}

// ---------------- T_lv3 = fold3x3(gathered PAN patches) / 9 ----------------
__global__ void tfold_kernel(const float* __restrict__ PAN, const int* __restrict__ Sa,
                             float* __restrict__ T) {
    int g = blockIdx.x * blockDim.x + threadIdx.x;
    if (g >= BB * CC * LL) return;
    int bc = g / LL, l = g - bc * LL;
    int b = bc >> 5;
    int y = div80(l), x = l - y * 80;
    const float* img = PAN + (size_t)bc * LL;
    const int* Sab = Sa + b * LL;
    float acc = 0.f;
    #pragma unroll
    for (int i = 0; i < 3; ++i) {
        int yp = y + 1 - i;
        if ((unsigned)yp >= 80u) continue;
        #pragma unroll
        for (int j = 0; j < 3; ++j) {
            int xp = x + 1 - j;
            if ((unsigned)xp >= 80u) continue;
            int a = Sab[yp * 80 + xp];
            int ya = div80(a), xa = a - ya * 80;
            int py = ya + i - 1, px = xa + j - 1;
            if ((unsigned)py < 80u && (unsigned)px < 80u) acc += img[py * 80 + px];
        }
    }
    T[g] = acc * (1.f / 9.f);
}

// ---------------- conv1: h = relu(conv3x3(concat(T,HSI), w1) + b1) ----------------
__global__ __launch_bounds__(256) void conv1_kernel(const float* __restrict__ T,
                                                    const float* __restrict__ HSI,
                                                    const float* __restrict__ w1,
                                                    const float* __restrict__ b1,
                                                    float* __restrict__ h) {
    __shared__ __align__(16) float wl[64][9][COG];   // 36.9 KB
    const int tid = threadIdx.x;
    const int co0 = blockIdx.y * COG;
    for (int idx = tid; idx < 64 * 9 * COG; idx += 256) {
        int cog = idx & (COG - 1);
        int rest = idx >> 4;
        int cin = rest / 9, tap = rest - cin * 9;
        wl[cin][tap][cog] = w1[(co0 + cog) * (64 * 9) + cin * 9 + tap];
    }
    __syncthreads();
    const int g = blockIdx.x * 256 + tid;
    const int b = g / LL, l = g - b * LL;
    const int y = div80(l), x = l - y * 80;
    float acc[COG];
    #pragma unroll
    for (int i = 0; i < COG; ++i) acc[i] = 0.f;
    for (int cin = 0; cin < 64; ++cin) {
        const float* img = (cin < CC) ? (T + (size_t)(b * CC + cin) * LL)
                                      : (HSI + (size_t)(b * CC + (cin - CC)) * LL);
        float tap[9];
        #pragma unroll
        for (int i = 0; i < 3; ++i)
            #pragma unroll
            for (int j = 0; j < 3; ++j) {
                int yy = y + i - 1, xx = x + j - 1;
                tap[i * 3 + j] = ((unsigned)yy < 80u && (unsigned)xx < 80u) ? img[yy * 80 + xx] : 0.f;
            }
        #pragma unroll
        for (int t9 = 0; t9 < 9; ++t9) {
            #pragma unroll
            for (int q4 = 0; q4 < COG / 4; ++q4) {
                const float4 wv = *reinterpret_cast<const float4*>(&wl[cin][t9][q4 * 4]);
                acc[q4 * 4 + 0] = fmaf(tap[t9], wv.x, acc[q4 * 4 + 0]);
                acc[q4 * 4 + 1] = fmaf(tap[t9], wv.y, acc[q4 * 4 + 1]);
                acc[q4 * 4 + 2] = fmaf(tap[t9], wv.z, acc[q4 * 4 + 2]);
                acc[q4 * 4 + 3] = fmaf(tap[t9], wv.w, acc[q4 * 4 + 3]);
            }
        }
    }
    #pragma unroll
    for (int cog = 0; cog < COG; ++cog) {
        float v = acc[cog] + b1[co0 + cog];
        h[(size_t)(b * CC + co0 + cog) * LL + l] = fmaxf(v, 0.f);
    }
}

// ---------------- conv2: out = (conv3x3(h, w2) + b2) * S + HSI ----------------
__global__ __launch_bounds__(256) void conv2_kernel(const float* __restrict__ hbuf,
                                                    const float* __restrict__ HSI,
                                                    const float* __restrict__ Sv,
                                                    const float* __restrict__ w2,
                                                    const float* __restrict__ b2,
                                                    float* __restrict__ out) {
    __shared__ __align__(16) float wl[CC][9][COG];   // 18.4 KB
    const int tid = threadIdx.x;
    const int co0 = blockIdx.y * COG;
    for (int idx = tid; idx < CC * 9 * COG; idx += 256) {
        int cog = idx & (COG - 1);
        int rest = idx >> 4;
        int cin = rest / 9, tap = rest - cin * 9;
        wl[cin][tap][cog] = w2[(co0 + cog) * (CC * 9) + cin * 9 + tap];
    }
    __syncthreads();
    const int g = blockIdx.x * 256 + tid;
    const int b = g / LL, l = g - b * LL;
    const int y = div80(l), x = l - y * 80;
    float acc[COG];
    #pragma unroll
    for (int i = 0; i < COG; ++i) acc[i] = 0.f;
    for (int cin = 0; cin < CC; ++cin) {
        const float* img = hbuf + (size_t)(b * CC + cin) * LL;
        float tap[9];
        #pragma unroll
        for (int i = 0; i < 3; ++i)
            #pragma unroll
            for (int j = 0; j < 3; ++j) {
                int yy = y + i - 1, xx = x + j - 1;
                tap[i * 3 + j] = ((unsigned)yy < 80u && (unsigned)xx < 80u) ? img[yy * 80 + xx] : 0.f;
            }
        #pragma unroll
        for (int t9 = 0; t9 < 9; ++t9) {
            #pragma unroll
            for (int q4 = 0; q4 < COG / 4; ++q4) {
                const float4 wv = *reinterpret_cast<const float4*>(&wl[cin][t9][q4 * 4]);
                acc[q4 * 4 + 0] = fmaf(tap[t9], wv.x, acc[q4 * 4 + 0]);
                acc[q4 * 4 + 1] = fmaf(tap[t9], wv.y, acc[q4 * 4 + 1]);
                acc[q4 * 4 + 2] = fmaf(tap[t9], wv.z, acc[q4 * 4 + 2]);
                acc[q4 * 4 + 3] = fmaf(tap[t9], wv.w, acc[q4 * 4 + 3]);
            }
        }
    }
    const float s = Sv[b * LL + l];
    #pragma unroll
    for (int cog = 0; cog < COG; ++cog) {
        int c = co0 + cog;
        out[(size_t)(b * CC + c) * LL + l] = fmaf(acc[cog] + b2[c], s, HSI[(size_t)(b * CC + c) * LL + l]);
    }
}

extern "C" void kernel_launch(void* const* d_in, const int* in_sizes, int n_in,
                              void* d_out, int out_size, void* d_ws, size_t ws_size,
                              hipStream_t stream) {
    const float* HSI = (const float*)d_in[0];
    const float* PAN = (const float*)d_in[1];
    const float* w1  = (const float*)d_in[2];
    const float* b1  = (const float*)d_in[3];
    const float* w2  = (const float*)d_in[4];
    const float* b2  = (const float*)d_in[5];
    float* out = (float*)d_out;

    char* ws = (char*)d_ws;
    size_t off = 0;
    auto alloc = [&](size_t bytes) -> void* {
        void* p = ws + off;
        off += (bytes + 255) & ~(size_t)255;
        return p;
    };
    float* partH = (float*)alloc((size_t)BB * CC * LL * 4);    // 1.64 MB
    float* partP = (float*)alloc((size_t)BB * CC * LL * 4);    // 1.64 MB
    float* invH  = (float*)alloc((size_t)BB * LL * 4);
    float* invP  = (float*)alloc((size_t)BB * LL * 4);
    char*  Apack = (char*) alloc((size_t)BB * 3 * LL * 256);   // 9.83 MB
    char*  Bpack = (char*) alloc((size_t)BB * 3 * LL * 256);   // 9.83 MB
    __half* tileMax8 = (__half*)alloc((size_t)BB * LL * NT8 * 2);    // 20.5 MB
    float* PANunf = (float*)alloc((size_t)BB * LL * 288 * 4);  // 14.75 MB
    float* HSIunf = (float*)alloc((size_t)BB * LL * 288 * 4);  // 14.75 MB
    float* Sv    = (float*)alloc((size_t)BB * LL * 4);
    int*   Sa    = (int*)  alloc((size_t)BB * LL * 4);
    // partH/partP are dead after prep2 -> reuse their space for T/hbuf
    float* T     = partH;
    float* hbuf  = partP;

    prep1_kernel<<<dim3((BB * CC * LL + 255) / 256), 256, 0, stream>>>(HSI, PAN, partH, partP);
    prep2_kernel<<<dim3((BB * LL + 255) / 256), 256, 0, stream>>>(partH, partP, invH, invP);
    pack_kernel<<<dim3((BB * 2 * LL * 36 + 255) / 256), 256, 0, stream>>>(HSI, PAN, invH, invP,
                                                                          Apack, Bpack, PANunf, HSIunf);
    simq_kernel<<<dim3(500), 256, 0, stream>>>(Apack, Bpack, tileMax8);
    scanfix_kernel<<<dim3(BB * LL / 4), 256, 0, stream>>>(PANunf, HSIunf, invH, invP, tileMax8, Sv, Sa);
    tfold_kernel<<<dim3((BB * CC * LL + 255) / 256), 256, 0, stream>>>(PAN, Sa, T);
    conv1_kernel<<<dim3(BB * LL / 256, CC / COG), 256, 0, stream>>>(T, HSI, w1, b1, hbuf);
    conv2_kernel<<<dim3(BB * LL / 256, CC / COG), 256, 0, stream>>>(hbuf, HSI, Sv, w2, b2, out);
}